// Round 14
// baseline (808.635 us; speedup 1.0000x reference)
//
#include <hip/hip_runtime.h>
#include <hip/hip_bf16.h>
#include <cstddef>

#define B 64
#define S 128
#define H 1024
#define V 32000
#define T 10
#define H3 3072
#define NCHUNK 250

typedef __bf16 bf16x8 __attribute__((ext_vector_type(8)));
typedef float f32x4 __attribute__((ext_vector_type(4)));
typedef unsigned short ushort8v __attribute__((ext_vector_type(8)));

__device__ inline unsigned short f2b(float f) {
    __hip_bfloat16 h = __float2bfloat16(f);
    return *reinterpret_cast<unsigned short*>(&h);
}
__device__ inline float b2f(unsigned short u) {
    return __uint_as_float(((unsigned)u) << 16);
}
__device__ inline float fast_tanh(float x) {
    float e = __expf(2.f * x);
    return 1.f - 2.f * __builtin_amdgcn_rcpf(e + 1.f);
}
__device__ inline float fast_sigmoid(float x) {
    return __builtin_amdgcn_rcpf(1.f + __expf(-x));
}

// async global->LDS, 16B per lane
__device__ inline void gload_lds16(const void* g, void* l) {
    __builtin_amdgcn_global_load_lds(
        (const __attribute__((address_space(1))) void*)g,
        (__attribute__((address_space(3))) void*)l, 16, 0, 0);
}

// bijective XCD swizzle (m204); nwg % 8 == 0 at all call sites
__device__ inline int xcd_swz(int orig, int nwg) {
    int q = nwg >> 3, r = nwg & 7;
    int xcd = orig & 7, idx = orig >> 3;
    int base = (xcd < r) ? xcd * (q + 1) : r * (q + 1) + (xcd - r) * q;
    return base + idx;
}

__device__ inline ushort8v cvt8(const float* p) {
    float4 f0 = *reinterpret_cast<const float4*>(p);
    float4 f1 = *reinterpret_cast<const float4*>(p + 4);
    ushort8v u;
    u[0] = f2b(f0.x); u[1] = f2b(f0.y); u[2] = f2b(f0.z); u[3] = f2b(f0.w);
    u[4] = f2b(f1.x); u[5] = f2b(f1.y); u[6] = f2b(f1.z); u[7] = f2b(f1.w);
    return u;
}

// ---------------- mega kernel: 3 fp32-input GEMMs + out_w conv + prep segments ----------------
// blocks: [0,512) d0=ua | [512,2048) d1=KV | [2048,2168) d2=gi_emb | [2168,18168) out_w conv
// [18168,20216) Wcat | [20216,20224) catbias | [20224,20256) hbf | [20256,20288) hbuf
#define G3_NB 20288
struct GemmDesc {
    const float* A;        // fp32 A (or emb base when gatherA)
    const float* Bw;       // fp32 B base
    const float* bias;
    void* C;
    int M, N;
    int brstride, bcoff;   // B row stride (floats), col offset
    int out_bf16, gatherA;
};

__global__ __launch_bounds__(512) void gemm3_kernel(GemmDesc d0, GemmDesc d1, GemmDesc d2,
                                                    const int* __restrict__ tgt,
                                                    const float* __restrict__ out_w,
                                                    unsigned short* __restrict__ outw_bf,
                                                    const float* __restrict__ gwh,
                                                    const float* __restrict__ Wa_w,
                                                    unsigned short* __restrict__ Wcat,
                                                    const float* __restrict__ gbh,
                                                    const float* __restrict__ Wa_b,
                                                    float* __restrict__ catbias,
                                                    const float* __restrict__ h0,
                                                    unsigned short* __restrict__ hbf,
                                                    float* __restrict__ hbuf) {
    const int bid = blockIdx.x;
    const int tid = threadIdx.x;
    if (bid >= 2168) {
        if (bid < 18168) {              // out_w fp32 -> bf16
            int i = (bid - 2168) * 512 + tid;
            float4 v = reinterpret_cast<const float4*>(out_w)[i];
            ushort4 o = { f2b(v.x), f2b(v.y), f2b(v.z), f2b(v.w) };
            reinterpret_cast<ushort4*>(outw_bf)[i] = o;
        } else if (bid < 20216) {       // Wcat = [gwh ; Wa_w] bf16
            int i = (bid - 18168) * 512 + tid;
            int e = i * 4, n = e >> 10, k = e & 1023;
            const float* src = (n < H3) ? (gwh + (size_t)n * H + k) : (Wa_w + (size_t)(n - H3) * H + k);
            float4 v = *reinterpret_cast<const float4*>(src);
            ushort4 o = { f2b(v.x), f2b(v.y), f2b(v.z), f2b(v.w) };
            reinterpret_cast<ushort4*>(Wcat)[i] = o;
        } else if (bid < 20224) {       // catbias
            int n = (bid - 20216) * 512 + tid;
            catbias[n] = (n < H3) ? gbh[n] : Wa_b[n - H3];
        } else if (bid < 20256) {       // hbf
            int i = (bid - 20224) * 512 + tid;
            float4 v = reinterpret_cast<const float4*>(h0)[i];
            ushort4 o = { f2b(v.x), f2b(v.y), f2b(v.z), f2b(v.w) };
            reinterpret_cast<ushort4*>(hbf)[i] = o;
        } else {                        // hbuf copy
            int i = (bid - 20256) * 512 + tid;
            reinterpret_cast<float4*>(hbuf)[i] = reinterpret_cast<const float4*>(h0)[i];
        }
        return;
    }

    __shared__ unsigned short As0[128 * 32], As1[128 * 32];
    __shared__ unsigned short Bs0[128 * 32], Bs1[128 * 32];
    GemmDesc d; int local, nwg;
    if (bid < 512)       { d = d0; local = bid;        nwg = 512;  }
    else if (bid < 2048) { d = d1; local = bid - 512;  nwg = 1536; }
    else                 { d = d2; local = bid - 2048; nwg = 120;  }
    local = xcd_swz(local, nwg);
    const int mtiles = d.M >> 7;
    const int bm = (local % mtiles) << 7, bn = (local / mtiles) << 7;
    const int lane = tid & 63, w = tid >> 6;
    const int wm = w >> 2, wn = w & 3;
    const int quad = lane >> 4, fr = lane & 15;
    f32x4 acc[4][2] = {};

    // fp32 staging map: thread -> row sr=tid>>2, chunk ck=(tid&3)>>1, col-in-chunk cc=((tid&1))*16
    const int sr = tid >> 2, q4 = tid & 3;
    const int ck = q4 >> 1, cc = (q4 & 1) * 16;
    const int gcol = ck * 32 + cc;                      // global col offset within 64-K tile
    unsigned short* asel = (ck ? As1 : As0) + sr * 32 + cc;
    unsigned short* bsel = (ck ? Bs1 : Bs0) + sr * 32 + cc;

    const float* arow;
    if (d.gatherA) {
        int m = bm + sr;                                // < 640
        int tt = m >> 6, bb = m & 63;
        int tok = (tt == 0) ? 0 : tgt[bb * T + tt - 1];
        arow = d.A + (size_t)tok * H;                   // emb row
    } else {
        arow = d.A + (size_t)(bm + sr) * H;
    }
    const float* brow = d.Bw + (size_t)(bn + sr) * d.brstride + d.bcoff;

    for (int k0 = 0; k0 < H; k0 += 64) {
        ushort8v ua0 = cvt8(arow + k0 + gcol);
        ushort8v ua1 = cvt8(arow + k0 + gcol + 8);
        ushort8v ub0 = cvt8(brow + k0 + gcol);
        ushort8v ub1 = cvt8(brow + k0 + gcol + 8);
        *reinterpret_cast<ushort8v*>(asel)     = ua0;
        *reinterpret_cast<ushort8v*>(asel + 8) = ua1;
        *reinterpret_cast<ushort8v*>(bsel)     = ub0;
        *reinterpret_cast<ushort8v*>(bsel + 8) = ub1;
        __syncthreads();
        #pragma unroll
        for (int ks = 0; ks < 2; ++ks) {
            const unsigned short* Asrc = ks ? As1 : As0;
            const unsigned short* Bsrc = ks ? Bs1 : Bs0;
            const int kg = quad * 8;
            bf16x8 a[4], bb[2];
            #pragma unroll
            for (int m = 0; m < 4; ++m)
                a[m] = *reinterpret_cast<const bf16x8*>(&Asrc[(64 * wm + 16 * m + fr) * 32 + kg]);
            #pragma unroll
            for (int n = 0; n < 2; ++n)
                bb[n] = *reinterpret_cast<const bf16x8*>(&Bsrc[(32 * wn + 16 * n + fr) * 32 + kg]);
            #pragma unroll
            for (int m = 0; m < 4; ++m)
                #pragma unroll
                for (int n = 0; n < 2; ++n)
                    acc[m][n] = __builtin_amdgcn_mfma_f32_16x16x32_bf16(a[m], bb[n], acc[m][n], 0, 0, 0);
        }
        __syncthreads();
    }
    #pragma unroll
    for (int n = 0; n < 2; ++n) {
        int col = bn + 32 * wn + 16 * n + fr;
        float bv = d.bias ? d.bias[col] : 0.f;
        #pragma unroll
        for (int m = 0; m < 4; ++m)
            #pragma unroll
            for (int i = 0; i < 4; ++i) {
                int row = bm + 64 * wm + 16 * m + quad * 4 + i;
                float v = acc[m][n][i] + bv;
                if (d.out_bf16)
                    ((unsigned short*)d.C)[(size_t)row * d.N + col] = f2b(v);
                else
                    ((float*)d.C)[(size_t)row * d.N + col] = v;
            }
    }
}

// ---------------- logits GEMM: BK=64 split-chunk gload_lds core + fused softmax stats ----------------
__global__ __launch_bounds__(512) void gemm_logits(const unsigned short* __restrict__ A,
                                                   const unsigned short* __restrict__ Bw,
                                                   const float* __restrict__ bias,
                                                   float* __restrict__ Cout,
                                                   float2* __restrict__ stats,
                                                   int M, int N, int K) {
    __shared__ unsigned short As0[128 * 32], As1[128 * 32];
    __shared__ unsigned short Bs0[128 * 32], Bs1[128 * 32];
    __shared__ float mred[128][4];
    __shared__ float sred[128][4];
    const int wg = xcd_swz(blockIdx.x, gridDim.x);
    const int mtiles = M >> 7;
    const int bm = (wg % mtiles) << 7, bn = (wg / mtiles) << 7;
    const int tid = threadIdx.x, lane = tid & 63, w = tid >> 6;
    const int wm = w >> 2, wn = w & 3;
    const int quad = lane >> 4, fr = lane & 15;
    f32x4 acc[4][2] = {};

    const int sr = w * 16 + (lane >> 2), sc = (lane & 3) * 8;
    const unsigned short* agp = A + (size_t)(bm + sr) * K + sc;
    const unsigned short* bgp = Bw + (size_t)(bn + sr) * K + sc;
    unsigned short* a0 = As0 + w * 512;
    unsigned short* a1 = As1 + w * 512;
    unsigned short* b0 = Bs0 + w * 512;
    unsigned short* b1 = Bs1 + w * 512;

    for (int k0 = 0; k0 < K; k0 += 64) {
        gload_lds16(agp + k0, a0);
        gload_lds16(agp + k0 + 32, a1);
        gload_lds16(bgp + k0, b0);
        gload_lds16(bgp + k0 + 32, b1);
        __syncthreads();
        #pragma unroll
        for (int ks = 0; ks < 2; ++ks) {
            const unsigned short* Asrc = ks ? As1 : As0;
            const unsigned short* Bsrc = ks ? Bs1 : Bs0;
            const int kg = quad * 8;
            bf16x8 a[4], bb[2];
            #pragma unroll
            for (int m = 0; m < 4; ++m)
                a[m] = *reinterpret_cast<const bf16x8*>(&Asrc[(64 * wm + 16 * m + fr) * 32 + kg]);
            #pragma unroll
            for (int n = 0; n < 2; ++n)
                bb[n] = *reinterpret_cast<const bf16x8*>(&Bsrc[(32 * wn + 16 * n + fr) * 32 + kg]);
            #pragma unroll
            for (int m = 0; m < 4; ++m)
                #pragma unroll
                for (int n = 0; n < 2; ++n)
                    acc[m][n] = __builtin_amdgcn_mfma_f32_16x16x32_bf16(a[m], bb[n], acc[m][n], 0, 0, 0);
        }
        __syncthreads();
    }

    #pragma unroll
    for (int n = 0; n < 2; ++n) {
        int col = bn + 32 * wn + 16 * n + fr;
        float bv = bias[col];
        #pragma unroll
        for (int m = 0; m < 4; ++m)
            #pragma unroll
            for (int i = 0; i < 4; ++i) {
                int row = bm + 64 * wm + 16 * m + quad * 4 + i;
                float v = acc[m][n][i] + bv;
                Cout[(size_t)row * N + col] = v;
                acc[m][n][i] = v;
            }
    }

    const int nchunk = N >> 7;
    #pragma unroll
    for (int m = 0; m < 4; ++m)
        #pragma unroll
        for (int i = 0; i < 4; ++i) {
            float x = fmaxf(acc[m][0][i], acc[m][1][i]);
            x = fmaxf(x, __shfl_xor(x, 1)); x = fmaxf(x, __shfl_xor(x, 2));
            x = fmaxf(x, __shfl_xor(x, 4)); x = fmaxf(x, __shfl_xor(x, 8));
            if (fr == 0) mred[64 * wm + 16 * m + quad * 4 + i][wn] = x;
        }
    __syncthreads();
    #pragma unroll
    for (int m = 0; m < 4; ++m)
        #pragma unroll
        for (int i = 0; i < 4; ++i) {
            int rl = 64 * wm + 16 * m + quad * 4 + i;
            float Mr = fmaxf(fmaxf(mred[rl][0], mred[rl][1]), fmaxf(mred[rl][2], mred[rl][3]));
            float sv = expf(acc[m][0][i] - Mr) + expf(acc[m][1][i] - Mr);
            sv += __shfl_xor(sv, 1); sv += __shfl_xor(sv, 2);
            sv += __shfl_xor(sv, 4); sv += __shfl_xor(sv, 8);
            if (fr == 0) sred[rl][wn] = sv;
        }
    __syncthreads();
    if (tid < 128) {
        float Mr = fmaxf(fmaxf(mred[tid][0], mred[tid][1]), fmaxf(mred[tid][2], mred[tid][3]));
        float Sv = sred[tid][0] + sred[tid][1] + sred[tid][2] + sred[tid][3];
        stats[(size_t)(bm + tid) * nchunk + (bn >> 7)] = make_float2(Mr, Sv);
    }
}

// ---------------- phase A: 64x32 tile, BK=128, grid 128, 256 thr (R11 verbatim) ----------------
__global__ __launch_bounds__(256) void gemm_smallA(const unsigned short* __restrict__ A,
                                                   const unsigned short* __restrict__ Bw,
                                                   const float* __restrict__ bias,
                                                   float* __restrict__ Cout) {
    __shared__ unsigned short As[64][136];
    __shared__ unsigned short Bs[32][136];
    const int bn = blockIdx.x * 32;
    const int tid = threadIdx.x, lane = tid & 63, w = tid >> 6;
    const int quad = lane >> 4, fr = lane & 15;
    f32x4 acc[2] = {};

    const int srA = tid >> 2, scA = (tid & 3) * 32;
    const int srB = tid >> 3, scB = (tid & 7) * 16;
    for (int k0 = 0; k0 < H; k0 += 128) {
        const unsigned short* ap = A + (size_t)srA * H + k0 + scA;
        #pragma unroll
        for (int u = 0; u < 4; ++u)
            *reinterpret_cast<bf16x8*>(&As[srA][scA + 8 * u]) =
                *reinterpret_cast<const bf16x8*>(ap + 8 * u);
        const unsigned short* bp = Bw + (size_t)(bn + srB) * H + k0 + scB;
        *reinterpret_cast<bf16x8*>(&Bs[srB][scB])     = *reinterpret_cast<const bf16x8*>(bp);
        *reinterpret_cast<bf16x8*>(&Bs[srB][scB + 8]) = *reinterpret_cast<const bf16x8*>(bp + 8);
        __syncthreads();
        #pragma unroll
        for (int ks = 0; ks < 4; ++ks) {
            const int kg = quad * 8 + 32 * ks;
            bf16x8 a = *reinterpret_cast<const bf16x8*>(&As[16 * w + fr][kg]);
            #pragma unroll
            for (int n = 0; n < 2; ++n) {
                bf16x8 bb = *reinterpret_cast<const bf16x8*>(&Bs[16 * n + fr][kg]);
                acc[n] = __builtin_amdgcn_mfma_f32_16x16x32_bf16(a, bb, acc[n], 0, 0, 0);
            }
        }
        __syncthreads();
    }
    #pragma unroll
    for (int n = 0; n < 2; ++n) {
        int col = bn + 16 * n + fr;
        float bv = bias[col];
        #pragma unroll
        for (int i = 0; i < 4; ++i) {
            int row = 16 * w + quad * 4 + i;
            Cout[(size_t)row * 4096 + col] = acc[n][i] + bv;
        }
    }
}

// ---------------- phase B: scores + softmax + KV-quarter + GRU-quarter (R11 verbatim) ----------------
__global__ __launch_bounds__(256) void stepB(const float* __restrict__ ghq,
                                             const unsigned short* __restrict__ keys,
                                             const unsigned short* __restrict__ KV,
                                             const float* __restrict__ va,
                                             const float* __restrict__ va_b,
                                             const float* __restrict__ gi_emb,
                                             float* __restrict__ h,
                                             unsigned short* __restrict__ hbf,
                                             unsigned short* __restrict__ outs_bf,
                                             float* __restrict__ attns,
                                             float* __restrict__ h_final, int t) {
    const int q = blockIdx.x, b = blockIdx.y;
    const int tid = threadIdx.x, lane = tid & 63, wv = tid >> 6;
    __shared__ float ssc[128];
    __shared__ float sw[128];
    __shared__ float red[4][64][13];

    float qv[16], vv[16];
    {
        const float* qp = ghq + (size_t)b * 4096 + H3 + lane * 16;
        const float* vp = va + lane * 16;
        #pragma unroll
        for (int j = 0; j < 16; ++j) { qv[j] = qp[j]; vv[j] = vp[j]; }
    }
    const float vab = va_b[0];
    const unsigned short* kb = keys + (size_t)b * S * H;
    for (int i = 0; i < 32; i += 2) {
        int s0 = wv * 32 + i;
        const unsigned short* kr0 = kb + (size_t)s0 * H + lane * 16;
        const unsigned short* kr1 = kr0 + H;
        ushort8v k00 = *reinterpret_cast<const ushort8v*>(kr0);
        ushort8v k01 = *reinterpret_cast<const ushort8v*>(kr0 + 8);
        ushort8v k10 = *reinterpret_cast<const ushort8v*>(kr1);
        ushort8v k11 = *reinterpret_cast<const ushort8v*>(kr1 + 8);
        float a0 = 0.f, a1 = 0.f;
        #pragma unroll
        for (int e = 0; e < 8; ++e) {
            a0 += fast_tanh(qv[e] + b2f(k00[e])) * vv[e];
            a1 += fast_tanh(qv[e] + b2f(k10[e])) * vv[e];
        }
        #pragma unroll
        for (int e = 0; e < 8; ++e) {
            a0 += fast_tanh(qv[8 + e] + b2f(k01[e])) * vv[8 + e];
            a1 += fast_tanh(qv[8 + e] + b2f(k11[e])) * vv[8 + e];
        }
        a0 += __shfl_xor(a0, 1);  a1 += __shfl_xor(a1, 1);
        a0 += __shfl_xor(a0, 2);  a1 += __shfl_xor(a1, 2);
        a0 += __shfl_xor(a0, 4);  a1 += __shfl_xor(a1, 4);
        a0 += __shfl_xor(a0, 8);  a1 += __shfl_xor(a1, 8);
        a0 += __shfl_xor(a0, 16); a1 += __shfl_xor(a1, 16);
        a0 += __shfl_xor(a0, 32); a1 += __shfl_xor(a1, 32);
        if (lane == 0) { ssc[s0] = a0 + vab; ssc[s0 + 1] = a1 + vab; }
    }
    __syncthreads();
    if (tid < 128) {
        float mx = -1e30f;
        #pragma unroll 8
        for (int s = 0; s < 128; ++s) mx = fmaxf(mx, ssc[s]);
        float sum = 0.f;
        #pragma unroll 8
        for (int s = 0; s < 128; ++s) sum += __expf(ssc[s] - mx);
        float wvv = __expf(ssc[tid] - mx) / sum;
        sw[tid] = wvv;
        if (q == 0) attns[((size_t)b * T + t) * S + tid] = wvv;
    }
    __syncthreads();

    const int j0 = q * 256 + lane * 4;
    float ar[4] = {}, az[4] = {}, an[4] = {};
    const unsigned short* kvb = KV + (size_t)b * S * H3 + j0;
    for (int i = 0; i < 32; i += 2) {
        int s0 = wv * 32 + i;
        float w0 = sw[s0], w1 = sw[s0 + 1];
        const unsigned short* r0 = kvb + (size_t)s0 * H3;
        const unsigned short* r1 = r0 + H3;
        uint2 u0a = *reinterpret_cast<const uint2*>(r0);
        uint2 u1a = *reinterpret_cast<const uint2*>(r0 + 1024);
        uint2 u2a = *reinterpret_cast<const uint2*>(r0 + 2048);
        uint2 u0b = *reinterpret_cast<const uint2*>(r1);
        uint2 u1b = *reinterpret_cast<const uint2*>(r1 + 1024);
        uint2 u2b = *reinterpret_cast<const uint2*>(r1 + 2048);
        ar[0] += w0 * b2f((unsigned short)(u0a.x & 0xffff)) + w1 * b2f((unsigned short)(u0b.x & 0xffff));
        ar[1] += w0 * b2f((unsigned short)(u0a.x >> 16))    + w1 * b2f((unsigned short)(u0b.x >> 16));
        ar[2] += w0 * b2f((unsigned short)(u0a.y & 0xffff)) + w1 * b2f((unsigned short)(u0b.y & 0xffff));
        ar[3] += w0 * b2f((unsigned short)(u0a.y >> 16))    + w1 * b2f((unsigned short)(u0b.y >> 16));
        az[0] += w0 * b2f((unsigned short)(u1a.x & 0xffff)) + w1 * b2f((unsigned short)(u1b.x & 0xffff));
        az[1] += w0 * b2f((unsigned short)(u1a.x >> 16))    + w1 * b2f((unsigned short)(u1b.x >> 16));
        az[2] += w0 * b2f((unsigned short)(u1a.y & 0xffff)) + w1 * b2f((unsigned short)(u1b.y & 0xffff));
        az[3] += w0 * b2f((unsigned short)(u1a.y >> 16))    + w1 * b2f((unsigned short)(u1b.y >> 16));
        an[0] += w0 * b2f((unsigned short)(u2a.x & 0xffff)) + w1 * b2f((unsigned short)(u2b.x & 0xffff));
        an[1] += w0 * b2f((unsigned short)(u2a.x >> 16))    + w1 * b2f((unsigned short)(u2b.x >> 16));
        an[2] += w0 * b2f((unsigned short)(u2a.y & 0xffff)) + w1 * b2f((unsigned short)(u2b.y & 0xffff));
        an[3] += w0 * b2f((unsigned short)(u2a.y >> 16))    + w1 * b2f((unsigned short)(u2b.y >> 16));
    }
    #pragma unroll
    for (int g = 0; g < 4; ++g) {
        red[wv][lane][g]     = ar[g];
        red[wv][lane][4 + g] = az[g];
        red[wv][lane][8 + g] = an[g];
    }
    __syncthreads();

    if (tid < 64) {
        float rr[4], zz[4], nn[4];
        #pragma unroll
        for (int g = 0; g < 4; ++g) {
            rr[g] = red[0][tid][g] + red[1][tid][g] + red[2][tid][g] + red[3][tid][g];
            zz[g] = red[0][tid][4+g] + red[1][tid][4+g] + red[2][tid][4+g] + red[3][tid][4+g];
            nn[g] = red[0][tid][8+g] + red[1][tid][8+g] + red[2][tid][8+g] + red[3][tid][8+g];
        }
        const int jj = q * 256 + tid * 4;
        const float* ge = gi_emb + ((size_t)t * B + b) * H3;
        const float* gh = ghq + (size_t)b * 4096;
        float geR[4], geZ[4], geN[4], ghR[4], ghZ[4], ghN[4], hv[4];
        *reinterpret_cast<float4*>(geR) = *reinterpret_cast<const float4*>(ge + jj);
        *reinterpret_cast<float4*>(geZ) = *reinterpret_cast<const float4*>(ge + 1024 + jj);
        *reinterpret_cast<float4*>(geN) = *reinterpret_cast<const float4*>(ge + 2048 + jj);
        *reinterpret_cast<float4*>(ghR) = *reinterpret_cast<const float4*>(gh + jj);
        *reinterpret_cast<float4*>(ghZ) = *reinterpret_cast<const float4*>(gh + 1024 + jj);
        *reinterpret_cast<float4*>(ghN) = *reinterpret_cast<const float4*>(gh + 2048 + jj);
        *reinterpret_cast<float4*>(hv)  = *reinterpret_cast<const float4*>(h + (size_t)b * H + jj);
        ushort4 hb;
        unsigned short* hbp = reinterpret_cast<unsigned short*>(&hb);
        #pragma unroll
        for (int i = 0; i < 4; ++i) {
            float r = fast_sigmoid(geR[i] + rr[i] + ghR[i]);
            float z = fast_sigmoid(geZ[i] + zz[i] + ghZ[i]);
            float n = fast_tanh(geN[i] + nn[i] + r * ghN[i]);
            hv[i] = (1.f - z) * n + z * hv[i];
            hbp[i] = f2b(hv[i]);
        }
        *reinterpret_cast<float4*>(h + (size_t)b * H + jj) = *reinterpret_cast<float4*>(hv);
        *reinterpret_cast<ushort4*>(hbf + (size_t)b * H + jj) = hb;
        *reinterpret_cast<ushort4*>(outs_bf + ((size_t)b * T + t) * H + jj) = hb;
        if (t == T - 1)
            *reinterpret_cast<float4*>(h_final + (size_t)b * H + jj) = *reinterpret_cast<float4*>(hv);
    }
}

// ---------------- fused LSE + subtract ----------------
__global__ void lsesub_kernel(const float2* __restrict__ stats, float* __restrict__ x) {
    const int row = blockIdx.x;
    const int tid = threadIdx.x;
    __shared__ float shm[256];
    __shared__ float shs[256];
    float mv = -1e30f, sv = 0.f;
    float2 st = make_float2(-1e30f, 0.f);
    if (tid < NCHUNK) { st = stats[(size_t)row * NCHUNK + tid]; mv = st.x; }
    shm[tid] = mv; __syncthreads();
    for (int off = 128; off > 0; off >>= 1) {
        if (tid < off) shm[tid] = fmaxf(shm[tid], shm[tid + off]);
        __syncthreads();
    }
    float M = shm[0]; __syncthreads();
    if (tid < NCHUNK) sv = st.y * expf(st.x - M);
    shs[tid] = sv; __syncthreads();
    for (int off = 128; off > 0; off >>= 1) {
        if (tid < off) shs[tid] += shs[tid + off];
        __syncthreads();
    }
    float L = M + logf(shs[0]);
    __syncthreads();
    float4* p = reinterpret_cast<float4*>(x + (size_t)row * V);
    for (int i = tid; i < V / 4; i += 256) {
        float4 v = p[i];
        v.x -= L; v.y -= L; v.z -= L; v.w -= L;
        p[i] = v;
    }
}

// ---------------- host ----------------

extern "C" void kernel_launch(void* const* d_in, const int* in_sizes, int n_in,
                              void* d_out, int out_size, void* d_ws, size_t ws_size,
                              hipStream_t stream) {
    const float* enc   = (const float*)d_in[0];
    const float* h0    = (const float*)d_in[1];
    const int*   tgt   = (const int*)d_in[2];
    const float* emb   = (const float*)d_in[3];
    const float* Wa_w  = (const float*)d_in[4];
    const float* Wa_b  = (const float*)d_in[5];
    const float* Ua_w  = (const float*)d_in[6];
    const float* Ua_b  = (const float*)d_in[7];
    const float* Va_w  = (const float*)d_in[8];
    const float* Va_b  = (const float*)d_in[9];
    const float* gwi   = (const float*)d_in[10];
    const float* gwh   = (const float*)d_in[11];
    const float* gbi   = (const float*)d_in[12];
    const float* gbh   = (const float*)d_in[13];
    const float* out_w = (const float*)d_in[14];
    const float* out_b = (const float*)d_in[15];

    float* out       = (float*)d_out;
    float* log_probs = out;                          // [B*T, V]
    float* h_final   = out + (size_t)B * T * V;      // [B, H]
    float* attns     = h_final + (size_t)B * H;      // [B, T, S]

    char* pp = (char*)d_ws;
    auto alloc = [&](size_t bytes) { char* r = pp; pp += (bytes + 255) & ~(size_t)255; return r; };
    unsigned short* ua_bf   = (unsigned short*)alloc((size_t)B * S * H * 2);
    unsigned short* outw_bf = (unsigned short*)alloc((size_t)V * H * 2);
    unsigned short* KV      = (unsigned short*)alloc((size_t)B * S * H3 * 2);
    unsigned short* Wcat    = (unsigned short*)alloc((size_t)4096 * H * 2);
    float*          catbias = (float*)alloc(4096 * 4);
    float*          gi_emb  = (float*)alloc((size_t)T * B * H3 * 4);
    float*          hbuf    = (float*)alloc((size_t)B * H * 4);
    unsigned short* hbf     = (unsigned short*)alloc((size_t)B * H * 2);
    float*          ghq     = (float*)alloc((size_t)B * 4096 * 4);
    unsigned short* outs_bf = (unsigned short*)alloc((size_t)B * T * H * 2);
    float2*         stats   = (float2*)alloc((size_t)B * T * NCHUNK * 8);

    // one launch: 3 fp32-input GEMMs (inline cvt; d2 gathers emb rows) + out_w conv + prep segments
    GemmDesc d0 = { enc, Ua_w, Ua_b, (void*)ua_bf,  B * S, H,  H,     0, 1, 0 };
    GemmDesc d1 = { enc, gwi,  nullptr, (void*)KV,  B * S, H3, 2 * H, H, 1, 0 };
    GemmDesc d2 = { emb, gwi,  gbi, (void*)gi_emb,  T * B, H3, 2 * H, 0, 0, 1 };
    gemm3_kernel<<<G3_NB, 512, 0, stream>>>(d0, d1, d2, tgt, out_w, outw_bf,
                                            gwh, Wa_w, Wcat, gbh, Wa_b, catbias,
                                            h0, hbf, hbuf);

    for (int t = 0; t < T; ++t) {
        gemm_smallA<<<128, 256, 0, stream>>>(hbf, Wcat, catbias, ghq);
        stepB<<<dim3(4, B), 256, 0, stream>>>(ghq, ua_bf, KV, Va_w, Va_b, gi_emb,
                                              hbuf, hbf, outs_bf, attns, h_final, t);
    }

    gemm_logits<<<(B * T / 128) * (V / 128), 512, 0, stream>>>(
        outs_bf, outw_bf, out_b, log_probs, stats, B * T, V, H);
    lsesub_kernel<<<B * T, 256, 0, stream>>>(stats, log_probs);
}

// Round 15
// 717.837 us; speedup vs baseline: 1.1265x; 1.1265x over previous
//
#include <hip/hip_runtime.h>
#include <hip/hip_bf16.h>
#include <cstddef>

#define B 64
#define S 128
#define H 1024
#define V 32000
#define T 10
#define H3 3072
#define NCHUNK 250

typedef __bf16 bf16x8 __attribute__((ext_vector_type(8)));
typedef float f32x4 __attribute__((ext_vector_type(4)));
typedef unsigned short ushort8v __attribute__((ext_vector_type(8)));

__device__ inline unsigned short f2b(float f) {
    __hip_bfloat16 h = __float2bfloat16(f);
    return *reinterpret_cast<unsigned short*>(&h);
}
__device__ inline float b2f(unsigned short u) {
    return __uint_as_float(((unsigned)u) << 16);
}
__device__ inline float fast_tanh(float x) {
    float e = __expf(2.f * x);
    return 1.f - 2.f * __builtin_amdgcn_rcpf(e + 1.f);
}
__device__ inline float fast_sigmoid(float x) {
    return __builtin_amdgcn_rcpf(1.f + __expf(-x));
}

// async global->LDS, 16B per lane
__device__ inline void gload_lds16(const void* g, void* l) {
    __builtin_amdgcn_global_load_lds(
        (const __attribute__((address_space(1))) void*)g,
        (__attribute__((address_space(3))) void*)l, 16, 0, 0);
}

// bijective XCD swizzle (m204)
__device__ inline int xcd_swz(int orig, int nwg) {
    int q = nwg >> 3, r = nwg & 7;
    int xcd = orig & 7, idx = orig >> 3;
    int base = (xcd < r) ? xcd * (q + 1) : r * (q + 1) + (xcd - r) * q;
    return base + idx;
}

// ---------------- prep kernel (R11 verbatim) ----------------
// [0,8192) enc | [8192,9216) Ua | [9216,13312) Wcat | [13312,16384) Wemb
// [16384,19456) Wctx | [19456,19472) catbias | [19472,20112) embg
// [20112,20176) hbf | [20176,20240) hbuf
#define PREP_NB 20240
__global__ void prep_kernel(const float* __restrict__ enc, unsigned short* __restrict__ enc_bf,
                            const float* __restrict__ Ua_w, unsigned short* __restrict__ Ua_bf,
                            const float* __restrict__ gwh, const float* __restrict__ Wa_w,
                            unsigned short* __restrict__ Wcat,
                            const float* __restrict__ gwi,
                            unsigned short* __restrict__ Wemb, unsigned short* __restrict__ Wctx,
                            const float* __restrict__ gbh, const float* __restrict__ Wa_b,
                            float* __restrict__ catbias,
                            const float* __restrict__ emb, const int* __restrict__ tgt,
                            unsigned short* __restrict__ embg,
                            const float* __restrict__ h0, unsigned short* __restrict__ hbf,
                            float* __restrict__ hbuf) {
    const int bid = blockIdx.x, tid = threadIdx.x;
    if (bid < 8192) {
        int i = bid * 256 + tid;
        float4 v = reinterpret_cast<const float4*>(enc)[i];
        ushort4 o = { f2b(v.x), f2b(v.y), f2b(v.z), f2b(v.w) };
        reinterpret_cast<ushort4*>(enc_bf)[i] = o;
    } else if (bid < 9216) {
        int i = (bid - 8192) * 256 + tid;
        float4 v = reinterpret_cast<const float4*>(Ua_w)[i];
        ushort4 o = { f2b(v.x), f2b(v.y), f2b(v.z), f2b(v.w) };
        reinterpret_cast<ushort4*>(Ua_bf)[i] = o;
    } else if (bid < 13312) {
        int i = (bid - 9216) * 256 + tid;
        int e = i * 4, n = e >> 10, k = e & 1023;
        const float* src = (n < H3) ? (gwh + (size_t)n * H + k) : (Wa_w + (size_t)(n - H3) * H + k);
        float4 v = *reinterpret_cast<const float4*>(src);
        ushort4 o = { f2b(v.x), f2b(v.y), f2b(v.z), f2b(v.w) };
        reinterpret_cast<ushort4*>(Wcat)[i] = o;
    } else if (bid < 16384) {
        int i = (bid - 13312) * 256 + tid;
        int e = i * 4, n = e >> 10, k = e & 1023;
        float4 v = *reinterpret_cast<const float4*>(gwi + (size_t)n * 2 * H + k);
        ushort4 o = { f2b(v.x), f2b(v.y), f2b(v.z), f2b(v.w) };
        reinterpret_cast<ushort4*>(Wemb)[i] = o;
    } else if (bid < 19456) {
        int i = (bid - 16384) * 256 + tid;
        int e = i * 4, n = e >> 10, k = e & 1023;
        float4 v = *reinterpret_cast<const float4*>(gwi + (size_t)n * 2 * H + H + k);
        ushort4 o = { f2b(v.x), f2b(v.y), f2b(v.z), f2b(v.w) };
        reinterpret_cast<ushort4*>(Wctx)[i] = o;
    } else if (bid < 19472) {
        int n = (bid - 19456) * 256 + tid;
        catbias[n] = (n < H3) ? gbh[n] : Wa_b[n - H3];
    } else if (bid < 20112) {
        int i = (bid - 19472) * 256 + tid;
        int e = i * 4;
        int t = e >> 16, rem = e & 65535;
        int b = rem >> 10, j = rem & 1023;
        int tok = (t == 0) ? 0 : tgt[b * T + (t - 1)];
        float4 v = *reinterpret_cast<const float4*>(emb + (size_t)tok * H + j);
        ushort4 o = { f2b(v.x), f2b(v.y), f2b(v.z), f2b(v.w) };
        *reinterpret_cast<ushort4*>(embg + ((size_t)t * B + b) * H + j) = o;
    } else if (bid < 20176) {
        int i = (bid - 20112) * 256 + tid;
        float4 v = reinterpret_cast<const float4*>(h0)[i];
        ushort4 o = { f2b(v.x), f2b(v.y), f2b(v.z), f2b(v.w) };
        reinterpret_cast<ushort4*>(hbf)[i] = o;
    } else {
        int i = (bid - 20176) * 256 + tid;
        reinterpret_cast<float4*>(hbuf)[i] = reinterpret_cast<const float4*>(h0)[i];
    }
}

// ---------------- merged 3-GEMM + out_w conversion; BK=64 split-chunk gload_lds core ----------------
struct GemmDesc {
    const unsigned short* A;
    const unsigned short* Bw;
    const float* bias;
    void* C;
    int M, N, out_bf16;
};

// blocks [0,512) d0 | [512,2048) d1 | [2048,2168) d2 | [2168,18168) out_w conv
__global__ __launch_bounds__(512) void gemm3_kernel(GemmDesc d0, GemmDesc d1, GemmDesc d2,
                                                    const float* __restrict__ out_w,
                                                    unsigned short* __restrict__ outw_bf) {
    __shared__ unsigned short As0[128 * 32], As1[128 * 32];
    __shared__ unsigned short Bs0[128 * 32], Bs1[128 * 32];
    const int bid = blockIdx.x;
    const int tid = threadIdx.x;
    if (bid >= 2168) {
        int i = (bid - 2168) * 512 + tid;
        float4 v = reinterpret_cast<const float4*>(out_w)[i];
        ushort4 o = { f2b(v.x), f2b(v.y), f2b(v.z), f2b(v.w) };
        reinterpret_cast<ushort4*>(outw_bf)[i] = o;
        return;
    }
    GemmDesc d; int local, nwg;
    if (bid < 512)       { d = d0; local = bid;        nwg = 512;  }
    else if (bid < 2048) { d = d1; local = bid - 512;  nwg = 1536; }
    else                 { d = d2; local = bid - 2048; nwg = 120;  }
    local = xcd_swz(local, nwg);
    const int mtiles = d.M >> 7;
    const int bm = (local % mtiles) << 7, bn = (local / mtiles) << 7;
    const int lane = tid & 63, w = tid >> 6;
    const int wm = w >> 2, wn = w & 3;
    const int quad = lane >> 4, fr = lane & 15;
    const int K = H;
    f32x4 acc[4][2] = {};

    // staging map (m97-proven): wave w stages rows [w*16,+16); lane l -> row +l/4, col (l&3)*8
    const int sr = w * 16 + (lane >> 2), sc = (lane & 3) * 8;
    const unsigned short* agp = d.A + (size_t)(bm + sr) * K + sc;
    const unsigned short* bgp = d.Bw + (size_t)(bn + sr) * K + sc;
    unsigned short* a0 = As0 + w * 512;
    unsigned short* a1 = As1 + w * 512;
    unsigned short* b0 = Bs0 + w * 512;
    unsigned short* b1 = Bs1 + w * 512;

    for (int k0 = 0; k0 < K; k0 += 64) {
        gload_lds16(agp + k0, a0);
        gload_lds16(agp + k0 + 32, a1);
        gload_lds16(bgp + k0, b0);
        gload_lds16(bgp + k0 + 32, b1);
        __syncthreads();
        #pragma unroll
        for (int ks = 0; ks < 2; ++ks) {
            const unsigned short* Asrc = ks ? As1 : As0;
            const unsigned short* Bsrc = ks ? Bs1 : Bs0;
            const int kg = quad * 8;
            bf16x8 a[4], bb[2];
            #pragma unroll
            for (int m = 0; m < 4; ++m)
                a[m] = *reinterpret_cast<const bf16x8*>(&Asrc[(64 * wm + 16 * m + fr) * 32 + kg]);
            #pragma unroll
            for (int n = 0; n < 2; ++n)
                bb[n] = *reinterpret_cast<const bf16x8*>(&Bsrc[(32 * wn + 16 * n + fr) * 32 + kg]);
            #pragma unroll
            for (int m = 0; m < 4; ++m)
                #pragma unroll
                for (int n = 0; n < 2; ++n)
                    acc[m][n] = __builtin_amdgcn_mfma_f32_16x16x32_bf16(a[m], bb[n], acc[m][n], 0, 0, 0);
        }
        __syncthreads();
    }
    #pragma unroll
    for (int n = 0; n < 2; ++n) {
        int col = bn + 32 * wn + 16 * n + fr;
        float bv = d.bias ? d.bias[col] : 0.f;
        #pragma unroll
        for (int m = 0; m < 4; ++m)
            #pragma unroll
            for (int i = 0; i < 4; ++i) {
                int row = bm + 64 * wm + 16 * m + quad * 4 + i;
                float v = acc[m][n][i] + bv;
                if (d.out_bf16)
                    ((unsigned short*)d.C)[(size_t)row * d.N + col] = f2b(v);
                else
                    ((float*)d.C)[(size_t)row * d.N + col] = v;
            }
    }
}

// ---------------- logits GEMM: BK=64 split-chunk core + fused softmax stats ----------------
__global__ __launch_bounds__(512) void gemm_logits(const unsigned short* __restrict__ A,
                                                   const unsigned short* __restrict__ Bw,
                                                   const float* __restrict__ bias,
                                                   float* __restrict__ Cout,
                                                   float2* __restrict__ stats,
                                                   int M, int N, int K) {
    __shared__ unsigned short As0[128 * 32], As1[128 * 32];
    __shared__ unsigned short Bs0[128 * 32], Bs1[128 * 32];
    __shared__ float mred[128][4];
    __shared__ float sred[128][4];
    const int wg = xcd_swz(blockIdx.x, gridDim.x);
    const int mtiles = M >> 7;
    const int bm = (wg % mtiles) << 7, bn = (wg / mtiles) << 7;
    const int tid = threadIdx.x, lane = tid & 63, w = tid >> 6;
    const int wm = w >> 2, wn = w & 3;
    const int quad = lane >> 4, fr = lane & 15;
    f32x4 acc[4][2] = {};

    const int sr = w * 16 + (lane >> 2), sc = (lane & 3) * 8;
    const unsigned short* agp = A + (size_t)(bm + sr) * K + sc;
    const unsigned short* bgp = Bw + (size_t)(bn + sr) * K + sc;
    unsigned short* a0 = As0 + w * 512;
    unsigned short* a1 = As1 + w * 512;
    unsigned short* b0 = Bs0 + w * 512;
    unsigned short* b1 = Bs1 + w * 512;

    for (int k0 = 0; k0 < K; k0 += 64) {
        gload_lds16(agp + k0, a0);
        gload_lds16(agp + k0 + 32, a1);
        gload_lds16(bgp + k0, b0);
        gload_lds16(bgp + k0 + 32, b1);
        __syncthreads();
        #pragma unroll
        for (int ks = 0; ks < 2; ++ks) {
            const unsigned short* Asrc = ks ? As1 : As0;
            const unsigned short* Bsrc = ks ? Bs1 : Bs0;
            const int kg = quad * 8;
            bf16x8 a[4], bb[2];
            #pragma unroll
            for (int m = 0; m < 4; ++m)
                a[m] = *reinterpret_cast<const bf16x8*>(&Asrc[(64 * wm + 16 * m + fr) * 32 + kg]);
            #pragma unroll
            for (int n = 0; n < 2; ++n)
                bb[n] = *reinterpret_cast<const bf16x8*>(&Bsrc[(32 * wn + 16 * n + fr) * 32 + kg]);
            #pragma unroll
            for (int m = 0; m < 4; ++m)
                #pragma unroll
                for (int n = 0; n < 2; ++n)
                    acc[m][n] = __builtin_amdgcn_mfma_f32_16x16x32_bf16(a[m], bb[n], acc[m][n], 0, 0, 0);
        }
        __syncthreads();
    }

    #pragma unroll
    for (int n = 0; n < 2; ++n) {
        int col = bn + 32 * wn + 16 * n + fr;
        float bv = bias[col];
        #pragma unroll
        for (int m = 0; m < 4; ++m)
            #pragma unroll
            for (int i = 0; i < 4; ++i) {
                int row = bm + 64 * wm + 16 * m + quad * 4 + i;
                float v = acc[m][n][i] + bv;
                Cout[(size_t)row * N + col] = v;
                acc[m][n][i] = v;
            }
    }

    const int nchunk = N >> 7;
    #pragma unroll
    for (int m = 0; m < 4; ++m)
        #pragma unroll
        for (int i = 0; i < 4; ++i) {
            float x = fmaxf(acc[m][0][i], acc[m][1][i]);
            x = fmaxf(x, __shfl_xor(x, 1)); x = fmaxf(x, __shfl_xor(x, 2));
            x = fmaxf(x, __shfl_xor(x, 4)); x = fmaxf(x, __shfl_xor(x, 8));
            if (fr == 0) mred[64 * wm + 16 * m + quad * 4 + i][wn] = x;
        }
    __syncthreads();
    #pragma unroll
    for (int m = 0; m < 4; ++m)
        #pragma unroll
        for (int i = 0; i < 4; ++i) {
            int rl = 64 * wm + 16 * m + quad * 4 + i;
            float Mr = fmaxf(fmaxf(mred[rl][0], mred[rl][1]), fmaxf(mred[rl][2], mred[rl][3]));
            float sv = expf(acc[m][0][i] - Mr) + expf(acc[m][1][i] - Mr);
            sv += __shfl_xor(sv, 1); sv += __shfl_xor(sv, 2);
            sv += __shfl_xor(sv, 4); sv += __shfl_xor(sv, 8);
            if (fr == 0) sred[rl][wn] = sv;
        }
    __syncthreads();
    if (tid < 128) {
        float Mr = fmaxf(fmaxf(mred[tid][0], mred[tid][1]), fmaxf(mred[tid][2], mred[tid][3]));
        float Sv = sred[tid][0] + sred[tid][1] + sred[tid][2] + sred[tid][3];
        stats[(size_t)(bm + tid) * nchunk + (bn >> 7)] = make_float2(Mr, Sv);
    }
}

// ---------------- phase A: 64x32 tile, BK=128, grid 128, 256 thr (R11 verbatim) ----------------
__global__ __launch_bounds__(256) void gemm_smallA(const unsigned short* __restrict__ A,
                                                   const unsigned short* __restrict__ Bw,
                                                   const float* __restrict__ bias,
                                                   float* __restrict__ Cout) {
    __shared__ unsigned short As[64][136];
    __shared__ unsigned short Bs[32][136];
    const int bn = blockIdx.x * 32;
    const int tid = threadIdx.x, lane = tid & 63, w = tid >> 6;
    const int quad = lane >> 4, fr = lane & 15;
    f32x4 acc[2] = {};

    const int srA = tid >> 2, scA = (tid & 3) * 32;
    const int srB = tid >> 3, scB = (tid & 7) * 16;
    for (int k0 = 0; k0 < H; k0 += 128) {
        const unsigned short* ap = A + (size_t)srA * H + k0 + scA;
        #pragma unroll
        for (int u = 0; u < 4; ++u)
            *reinterpret_cast<bf16x8*>(&As[srA][scA + 8 * u]) =
                *reinterpret_cast<const bf16x8*>(ap + 8 * u);
        const unsigned short* bp = Bw + (size_t)(bn + srB) * H + k0 + scB;
        *reinterpret_cast<bf16x8*>(&Bs[srB][scB])     = *reinterpret_cast<const bf16x8*>(bp);
        *reinterpret_cast<bf16x8*>(&Bs[srB][scB + 8]) = *reinterpret_cast<const bf16x8*>(bp + 8);
        __syncthreads();
        #pragma unroll
        for (int ks = 0; ks < 4; ++ks) {
            const int kg = quad * 8 + 32 * ks;
            bf16x8 a = *reinterpret_cast<const bf16x8*>(&As[16 * w + fr][kg]);
            #pragma unroll
            for (int n = 0; n < 2; ++n) {
                bf16x8 bb = *reinterpret_cast<const bf16x8*>(&Bs[16 * n + fr][kg]);
                acc[n] = __builtin_amdgcn_mfma_f32_16x16x32_bf16(a, bb, acc[n], 0, 0, 0);
            }
        }
        __syncthreads();
    }
    #pragma unroll
    for (int n = 0; n < 2; ++n) {
        int col = bn + 16 * n + fr;
        float bv = bias[col];
        #pragma unroll
        for (int i = 0; i < 4; ++i) {
            int row = 16 * w + quad * 4 + i;
            Cout[(size_t)row * 4096 + col] = acc[n][i] + bv;
        }
    }
}

// ---------------- phase B: scores + softmax + KV-quarter + GRU-quarter (R11 verbatim) ----------------
__global__ __launch_bounds__(256) void stepB(const float* __restrict__ ghq,
                                             const unsigned short* __restrict__ keys,
                                             const unsigned short* __restrict__ KV,
                                             const float* __restrict__ va,
                                             const float* __restrict__ va_b,
                                             const float* __restrict__ gi_emb,
                                             float* __restrict__ h,
                                             unsigned short* __restrict__ hbf,
                                             unsigned short* __restrict__ outs_bf,
                                             float* __restrict__ attns,
                                             float* __restrict__ h_final, int t) {
    const int q = blockIdx.x, b = blockIdx.y;
    const int tid = threadIdx.x, lane = tid & 63, wv = tid >> 6;
    __shared__ float ssc[128];
    __shared__ float sw[128];
    __shared__ float red[4][64][13];

    float qv[16], vv[16];
    {
        const float* qp = ghq + (size_t)b * 4096 + H3 + lane * 16;
        const float* vp = va + lane * 16;
        #pragma unroll
        for (int j = 0; j < 16; ++j) { qv[j] = qp[j]; vv[j] = vp[j]; }
    }
    const float vab = va_b[0];
    const unsigned short* kb = keys + (size_t)b * S * H;
    for (int i = 0; i < 32; i += 2) {
        int s0 = wv * 32 + i;
        const unsigned short* kr0 = kb + (size_t)s0 * H + lane * 16;
        const unsigned short* kr1 = kr0 + H;
        ushort8v k00 = *reinterpret_cast<const ushort8v*>(kr0);
        ushort8v k01 = *reinterpret_cast<const ushort8v*>(kr0 + 8);
        ushort8v k10 = *reinterpret_cast<const ushort8v*>(kr1);
        ushort8v k11 = *reinterpret_cast<const ushort8v*>(kr1 + 8);
        float a0 = 0.f, a1 = 0.f;
        #pragma unroll
        for (int e = 0; e < 8; ++e) {
            a0 += fast_tanh(qv[e] + b2f(k00[e])) * vv[e];
            a1 += fast_tanh(qv[e] + b2f(k10[e])) * vv[e];
        }
        #pragma unroll
        for (int e = 0; e < 8; ++e) {
            a0 += fast_tanh(qv[8 + e] + b2f(k01[e])) * vv[8 + e];
            a1 += fast_tanh(qv[8 + e] + b2f(k11[e])) * vv[8 + e];
        }
        a0 += __shfl_xor(a0, 1);  a1 += __shfl_xor(a1, 1);
        a0 += __shfl_xor(a0, 2);  a1 += __shfl_xor(a1, 2);
        a0 += __shfl_xor(a0, 4);  a1 += __shfl_xor(a1, 4);
        a0 += __shfl_xor(a0, 8);  a1 += __shfl_xor(a1, 8);
        a0 += __shfl_xor(a0, 16); a1 += __shfl_xor(a1, 16);
        a0 += __shfl_xor(a0, 32); a1 += __shfl_xor(a1, 32);
        if (lane == 0) { ssc[s0] = a0 + vab; ssc[s0 + 1] = a1 + vab; }
    }
    __syncthreads();
    if (tid < 128) {
        float mx = -1e30f;
        #pragma unroll 8
        for (int s = 0; s < 128; ++s) mx = fmaxf(mx, ssc[s]);
        float sum = 0.f;
        #pragma unroll 8
        for (int s = 0; s < 128; ++s) sum += __expf(ssc[s] - mx);
        float wvv = __expf(ssc[tid] - mx) / sum;
        sw[tid] = wvv;
        if (q == 0) attns[((size_t)b * T + t) * S + tid] = wvv;
    }
    __syncthreads();

    const int j0 = q * 256 + lane * 4;
    float ar[4] = {}, az[4] = {}, an[4] = {};
    const unsigned short* kvb = KV + (size_t)b * S * H3 + j0;
    for (int i = 0; i < 32; i += 2) {
        int s0 = wv * 32 + i;
        float w0 = sw[s0], w1 = sw[s0 + 1];
        const unsigned short* r0 = kvb + (size_t)s0 * H3;
        const unsigned short* r1 = r0 + H3;
        uint2 u0a = *reinterpret_cast<const uint2*>(r0);
        uint2 u1a = *reinterpret_cast<const uint2*>(r0 + 1024);
        uint2 u2a = *reinterpret_cast<const uint2*>(r0 + 2048);
        uint2 u0b = *reinterpret_cast<const uint2*>(r1);
        uint2 u1b = *reinterpret_cast<const uint2*>(r1 + 1024);
        uint2 u2b = *reinterpret_cast<const uint2*>(r1 + 2048);
        ar[0] += w0 * b2f((unsigned short)(u0a.x & 0xffff)) + w1 * b2f((unsigned short)(u0b.x & 0xffff));
        ar[1] += w0 * b2f((unsigned short)(u0a.x >> 16))    + w1 * b2f((unsigned short)(u0b.x >> 16));
        ar[2] += w0 * b2f((unsigned short)(u0a.y & 0xffff)) + w1 * b2f((unsigned short)(u0b.y & 0xffff));
        ar[3] += w0 * b2f((unsigned short)(u0a.y >> 16))    + w1 * b2f((unsigned short)(u0b.y >> 16));
        az[0] += w0 * b2f((unsigned short)(u1a.x & 0xffff)) + w1 * b2f((unsigned short)(u1b.x & 0xffff));
        az[1] += w0 * b2f((unsigned short)(u1a.x >> 16))    + w1 * b2f((unsigned short)(u1b.x >> 16));
        az[2] += w0 * b2f((unsigned short)(u1a.y & 0xffff)) + w1 * b2f((unsigned short)(u1b.y & 0xffff));
        az[3] += w0 * b2f((unsigned short)(u1a.y >> 16))    + w1 * b2f((unsigned short)(u1b.y >> 16));
        an[0] += w0 * b2f((unsigned short)(u2a.x & 0xffff)) + w1 * b2f((unsigned short)(u2b.x & 0xffff));
        an[1] += w0 * b2f((unsigned short)(u2a.x >> 16))    + w1 * b2f((unsigned short)(u2b.x >> 16));
        an[2] += w0 * b2f((unsigned short)(u2a.y & 0xffff)) + w1 * b2f((unsigned short)(u2b.y & 0xffff));
        an[3] += w0 * b2f((unsigned short)(u2a.y >> 16))    + w1 * b2f((unsigned short)(u2b.y >> 16));
    }
    #pragma unroll
    for (int g = 0; g < 4; ++g) {
        red[wv][lane][g]     = ar[g];
        red[wv][lane][4 + g] = az[g];
        red[wv][lane][8 + g] = an[g];
    }
    __syncthreads();

    if (tid < 64) {
        float rr[4], zz[4], nn[4];
        #pragma unroll
        for (int g = 0; g < 4; ++g) {
            rr[g] = red[0][tid][g] + red[1][tid][g] + red[2][tid][g] + red[3][tid][g];
            zz[g] = red[0][tid][4+g] + red[1][tid][4+g] + red[2][tid][4+g] + red[3][tid][4+g];
            nn[g] = red[0][tid][8+g] + red[1][tid][8+g] + red[2][tid][8+g] + red[3][tid][8+g];
        }
        const int jj = q * 256 + tid * 4;
        const float* ge = gi_emb + ((size_t)t * B + b) * H3;
        const float* gh = ghq + (size_t)b * 4096;
        float geR[4], geZ[4], geN[4], ghR[4], ghZ[4], ghN[4], hv[4];
        *reinterpret_cast<float4*>(geR) = *reinterpret_cast<const float4*>(ge + jj);
        *reinterpret_cast<float4*>(geZ) = *reinterpret_cast<const float4*>(ge + 1024 + jj);
        *reinterpret_cast<float4*>(geN) = *reinterpret_cast<const float4*>(ge + 2048 + jj);
        *reinterpret_cast<float4*>(ghR) = *reinterpret_cast<const float4*>(gh + jj);
        *reinterpret_cast<float4*>(ghZ) = *reinterpret_cast<const float4*>(gh + 1024 + jj);
        *reinterpret_cast<float4*>(ghN) = *reinterpret_cast<const float4*>(gh + 2048 + jj);
        *reinterpret_cast<float4*>(hv)  = *reinterpret_cast<const float4*>(h + (size_t)b * H + jj);
        ushort4 hb;
        unsigned short* hbp = reinterpret_cast<unsigned short*>(&hb);
        #pragma unroll
        for (int i = 0; i < 4; ++i) {
            float r = fast_sigmoid(geR[i] + rr[i] + ghR[i]);
            float z = fast_sigmoid(geZ[i] + zz[i] + ghZ[i]);
            float n = fast_tanh(geN[i] + nn[i] + r * ghN[i]);
            hv[i] = (1.f - z) * n + z * hv[i];
            hbp[i] = f2b(hv[i]);
        }
        *reinterpret_cast<float4*>(h + (size_t)b * H + jj) = *reinterpret_cast<float4*>(hv);
        *reinterpret_cast<ushort4*>(hbf + (size_t)b * H + jj) = hb;
        *reinterpret_cast<ushort4*>(outs_bf + ((size_t)b * T + t) * H + jj) = hb;
        if (t == T - 1)
            *reinterpret_cast<float4*>(h_final + (size_t)b * H + jj) = *reinterpret_cast<float4*>(hv);
    }
}

// ---------------- fused LSE + subtract ----------------
__global__ void lsesub_kernel(const float2* __restrict__ stats, float* __restrict__ x) {
    const int row = blockIdx.x;
    const int tid = threadIdx.x;
    __shared__ float shm[256];
    __shared__ float shs[256];
    float mv = -1e30f, sv = 0.f;
    float2 st = make_float2(-1e30f, 0.f);
    if (tid < NCHUNK) { st = stats[(size_t)row * NCHUNK + tid]; mv = st.x; }
    shm[tid] = mv; __syncthreads();
    for (int off = 128; off > 0; off >>= 1) {
        if (tid < off) shm[tid] = fmaxf(shm[tid], shm[tid + off]);
        __syncthreads();
    }
    float M = shm[0]; __syncthreads();
    if (tid < NCHUNK) sv = st.y * expf(st.x - M);
    shs[tid] = sv; __syncthreads();
    for (int off = 128; off > 0; off >>= 1) {
        if (tid < off) shs[tid] += shs[tid + off];
        __syncthreads();
    }
    float L = M + logf(shs[0]);
    __syncthreads();
    float4* p = reinterpret_cast<float4*>(x + (size_t)row * V);
    for (int i = tid; i < V / 4; i += 256) {
        float4 v = p[i];
        v.x -= L; v.y -= L; v.z -= L; v.w -= L;
        p[i] = v;
    }
}

// ---------------- host ----------------

extern "C" void kernel_launch(void* const* d_in, const int* in_sizes, int n_in,
                              void* d_out, int out_size, void* d_ws, size_t ws_size,
                              hipStream_t stream) {
    const float* enc   = (const float*)d_in[0];
    const float* h0    = (const float*)d_in[1];
    const int*   tgt   = (const int*)d_in[2];
    const float* emb   = (const float*)d_in[3];
    const float* Wa_w  = (const float*)d_in[4];
    const float* Wa_b  = (const float*)d_in[5];
    const float* Ua_w  = (const float*)d_in[6];
    const float* Ua_b  = (const float*)d_in[7];
    const float* Va_w  = (const float*)d_in[8];
    const float* Va_b  = (const float*)d_in[9];
    const float* gwi   = (const float*)d_in[10];
    const float* gwh   = (const float*)d_in[11];
    const float* gbi   = (const float*)d_in[12];
    const float* gbh   = (const float*)d_in[13];
    const float* out_w = (const float*)d_in[14];
    const float* out_b = (const float*)d_in[15];

    float* out       = (float*)d_out;
    float* log_probs = out;                          // [B*T, V]
    float* h_final   = out + (size_t)B * T * V;      // [B, H]
    float* attns     = h_final + (size_t)B * H;      // [B, T, S]

    char* pp = (char*)d_ws;
    auto alloc = [&](size_t bytes) { char* r = pp; pp += (bytes + 255) & ~(size_t)255; return r; };
    unsigned short* ua_bf   = (unsigned short*)alloc((size_t)B * S * H * 2);
    unsigned short* enc_bf  = (unsigned short*)alloc((size_t)B * S * H * 2);
    unsigned short* outw_bf = (unsigned short*)alloc((size_t)V * H * 2);
    unsigned short* KV      = (unsigned short*)alloc((size_t)B * S * H3 * 2);
    unsigned short* Ua_bf   = (unsigned short*)alloc((size_t)H * H * 2);
    unsigned short* Wcat    = (unsigned short*)alloc((size_t)4096 * H * 2);
    unsigned short* Wctx    = (unsigned short*)alloc((size_t)H3 * H * 2);
    unsigned short* Wemb    = (unsigned short*)alloc((size_t)H3 * H * 2);
    float*          catbias = (float*)alloc(4096 * 4);
    unsigned short* embg    = (unsigned short*)alloc((size_t)T * B * H * 2);
    float*          gi_emb  = (float*)alloc((size_t)T * B * H3 * 4);
    float*          hbuf    = (float*)alloc((size_t)B * H * 4);
    unsigned short* hbf     = (unsigned short*)alloc((size_t)B * H * 2);
    float*          ghq     = (float*)alloc((size_t)B * 4096 * 4);
    unsigned short* outs_bf = (unsigned short*)alloc((size_t)B * T * H * 2);
    float2*         stats   = (float2*)alloc((size_t)B * T * NCHUNK * 8);

    prep_kernel<<<PREP_NB, 256, 0, stream>>>(enc, enc_bf, Ua_w, Ua_bf,
                                             gwh, Wa_w, Wcat, gwi, Wemb, Wctx,
                                             gbh, Wa_b, catbias, emb, tgt, embg,
                                             h0, hbf, hbuf);

    GemmDesc d0 = { enc_bf, Ua_bf, Ua_b, (void*)ua_bf,  B * S, H,  1 };
    GemmDesc d1 = { enc_bf, Wctx,  nullptr, (void*)KV,  B * S, H3, 1 };
    GemmDesc d2 = { embg,   Wemb,  gbi, (void*)gi_emb,  T * B, H3, 0 };
    gemm3_kernel<<<18168, 512, 0, stream>>>(d0, d1, d2, out_w, outw_bf);

    for (int t = 0; t < T; ++t) {
        gemm_smallA<<<128, 256, 0, stream>>>(hbf, Wcat, catbias, ghq);
        stepB<<<dim3(4, B), 256, 0, stream>>>(ghq, ua_bf, KV, Va_w, Va_b, gi_emb,
                                              hbuf, hbf, outs_bf, attns, h_final, t);
    }

    gemm_logits<<<(B * T / 128) * (V / 128), 512, 0, stream>>>(
        outs_bf, outw_bf, out_b, log_probs, stats, B * T, V, H);
    lsesub_kernel<<<B * T, 256, 0, stream>>>(stats, log_probs);
}

// Round 16
// 698.124 us; speedup vs baseline: 1.1583x; 1.0282x over previous
//
#include <hip/hip_runtime.h>
#include <hip/hip_bf16.h>
#include <cstddef>

#define B 64
#define S 128
#define H 1024
#define V 32000
#define T 10
#define H3 3072
#define NCHUNK 250
#define CONV_BLKS 800     // per stepB launch; 800*1024 f4 * 10 launches = V*H/4

typedef __bf16 bf16x8 __attribute__((ext_vector_type(8)));
typedef float f32x4 __attribute__((ext_vector_type(4)));
typedef unsigned short ushort8v __attribute__((ext_vector_type(8)));

__device__ inline unsigned short f2b(float f) {
    __hip_bfloat16 h = __float2bfloat16(f);
    return *reinterpret_cast<unsigned short*>(&h);
}
__device__ inline float b2f(unsigned short u) {
    return __uint_as_float(((unsigned)u) << 16);
}
__device__ inline float fast_tanh(float x) {
    float e = __expf(2.f * x);
    return 1.f - 2.f * __builtin_amdgcn_rcpf(e + 1.f);
}
__device__ inline float fast_sigmoid(float x) {
    return __builtin_amdgcn_rcpf(1.f + __expf(-x));
}

// async global->LDS, 16B per lane
__device__ inline void gload_lds16(const void* g, void* l) {
    __builtin_amdgcn_global_load_lds(
        (const __attribute__((address_space(1))) void*)g,
        (__attribute__((address_space(3))) void*)l, 16, 0, 0);
}

// bijective XCD swizzle (m204)
__device__ inline int xcd_swz(int orig, int nwg) {
    int q = nwg >> 3, r = nwg & 7;
    int xcd = orig & 7, idx = orig >> 3;
    int base = (xcd < r) ? xcd * (q + 1) : r * (q + 1) + (xcd - r) * q;
    return base + idx;
}

// ---------------- prep kernel (R11 verbatim) ----------------
// [0,8192) enc | [8192,9216) Ua | [9216,13312) Wcat | [13312,16384) Wemb
// [16384,19456) Wctx | [19456,19472) catbias | [19472,20112) embg
// [20112,20176) hbf | [20176,20240) hbuf
#define PREP_NB 20240
__global__ void prep_kernel(const float* __restrict__ enc, unsigned short* __restrict__ enc_bf,
                            const float* __restrict__ Ua_w, unsigned short* __restrict__ Ua_bf,
                            const float* __restrict__ gwh, const float* __restrict__ Wa_w,
                            unsigned short* __restrict__ Wcat,
                            const float* __restrict__ gwi,
                            unsigned short* __restrict__ Wemb, unsigned short* __restrict__ Wctx,
                            const float* __restrict__ gbh, const float* __restrict__ Wa_b,
                            float* __restrict__ catbias,
                            const float* __restrict__ emb, const int* __restrict__ tgt,
                            unsigned short* __restrict__ embg,
                            const float* __restrict__ h0, unsigned short* __restrict__ hbf,
                            float* __restrict__ hbuf) {
    const int bid = blockIdx.x, tid = threadIdx.x;
    if (bid < 8192) {
        int i = bid * 256 + tid;
        float4 v = reinterpret_cast<const float4*>(enc)[i];
        ushort4 o = { f2b(v.x), f2b(v.y), f2b(v.z), f2b(v.w) };
        reinterpret_cast<ushort4*>(enc_bf)[i] = o;
    } else if (bid < 9216) {
        int i = (bid - 8192) * 256 + tid;
        float4 v = reinterpret_cast<const float4*>(Ua_w)[i];
        ushort4 o = { f2b(v.x), f2b(v.y), f2b(v.z), f2b(v.w) };
        reinterpret_cast<ushort4*>(Ua_bf)[i] = o;
    } else if (bid < 13312) {
        int i = (bid - 9216) * 256 + tid;
        int e = i * 4, n = e >> 10, k = e & 1023;
        const float* src = (n < H3) ? (gwh + (size_t)n * H + k) : (Wa_w + (size_t)(n - H3) * H + k);
        float4 v = *reinterpret_cast<const float4*>(src);
        ushort4 o = { f2b(v.x), f2b(v.y), f2b(v.z), f2b(v.w) };
        reinterpret_cast<ushort4*>(Wcat)[i] = o;
    } else if (bid < 16384) {
        int i = (bid - 13312) * 256 + tid;
        int e = i * 4, n = e >> 10, k = e & 1023;
        float4 v = *reinterpret_cast<const float4*>(gwi + (size_t)n * 2 * H + k);
        ushort4 o = { f2b(v.x), f2b(v.y), f2b(v.z), f2b(v.w) };
        reinterpret_cast<ushort4*>(Wemb)[i] = o;
    } else if (bid < 19456) {
        int i = (bid - 16384) * 256 + tid;
        int e = i * 4, n = e >> 10, k = e & 1023;
        float4 v = *reinterpret_cast<const float4*>(gwi + (size_t)n * 2 * H + H + k);
        ushort4 o = { f2b(v.x), f2b(v.y), f2b(v.z), f2b(v.w) };
        reinterpret_cast<ushort4*>(Wctx)[i] = o;
    } else if (bid < 19472) {
        int n = (bid - 19456) * 256 + tid;
        catbias[n] = (n < H3) ? gbh[n] : Wa_b[n - H3];
    } else if (bid < 20112) {
        int i = (bid - 19472) * 256 + tid;
        int e = i * 4;
        int t = e >> 16, rem = e & 65535;
        int b = rem >> 10, j = rem & 1023;
        int tok = (t == 0) ? 0 : tgt[b * T + (t - 1)];
        float4 v = *reinterpret_cast<const float4*>(emb + (size_t)tok * H + j);
        ushort4 o = { f2b(v.x), f2b(v.y), f2b(v.z), f2b(v.w) };
        *reinterpret_cast<ushort4*>(embg + ((size_t)t * B + b) * H + j) = o;
    } else if (bid < 20176) {
        int i = (bid - 20112) * 256 + tid;
        float4 v = reinterpret_cast<const float4*>(h0)[i];
        ushort4 o = { f2b(v.x), f2b(v.y), f2b(v.z), f2b(v.w) };
        reinterpret_cast<ushort4*>(hbf)[i] = o;
    } else {
        int i = (bid - 20176) * 256 + tid;
        reinterpret_cast<float4*>(hbuf)[i] = reinterpret_cast<const float4*>(h0)[i];
    }
}

// ---------------- merged 3-GEMM; BK=64 split-chunk gload_lds core (no conv) ----------------
struct GemmDesc {
    const unsigned short* A;
    const unsigned short* Bw;
    const float* bias;
    void* C;
    int M, N, out_bf16;
};

// blocks [0,512) d0 | [512,2048) d1 | [2048,2168) d2
__global__ __launch_bounds__(512) void gemm3_kernel(GemmDesc d0, GemmDesc d1, GemmDesc d2) {
    __shared__ unsigned short As0[128 * 32], As1[128 * 32];
    __shared__ unsigned short Bs0[128 * 32], Bs1[128 * 32];
    const int bid = blockIdx.x;
    const int tid = threadIdx.x;
    GemmDesc d; int local, nwg;
    if (bid < 512)       { d = d0; local = bid;        nwg = 512;  }
    else if (bid < 2048) { d = d1; local = bid - 512;  nwg = 1536; }
    else                 { d = d2; local = bid - 2048; nwg = 120;  }
    local = xcd_swz(local, nwg);
    const int mtiles = d.M >> 7;
    const int bm = (local % mtiles) << 7, bn = (local / mtiles) << 7;
    const int lane = tid & 63, w = tid >> 6;
    const int wm = w >> 2, wn = w & 3;
    const int quad = lane >> 4, fr = lane & 15;
    const int K = H;
    f32x4 acc[4][2] = {};

    const int sr = w * 16 + (lane >> 2), sc = (lane & 3) * 8;
    const unsigned short* agp = d.A + (size_t)(bm + sr) * K + sc;
    const unsigned short* bgp = d.Bw + (size_t)(bn + sr) * K + sc;
    unsigned short* a0 = As0 + w * 512;
    unsigned short* a1 = As1 + w * 512;
    unsigned short* b0 = Bs0 + w * 512;
    unsigned short* b1 = Bs1 + w * 512;

    for (int k0 = 0; k0 < K; k0 += 64) {
        gload_lds16(agp + k0, a0);
        gload_lds16(agp + k0 + 32, a1);
        gload_lds16(bgp + k0, b0);
        gload_lds16(bgp + k0 + 32, b1);
        __syncthreads();
        #pragma unroll
        for (int ks = 0; ks < 2; ++ks) {
            const unsigned short* Asrc = ks ? As1 : As0;
            const unsigned short* Bsrc = ks ? Bs1 : Bs0;
            const int kg = quad * 8;
            bf16x8 a[4], bb[2];
            #pragma unroll
            for (int m = 0; m < 4; ++m)
                a[m] = *reinterpret_cast<const bf16x8*>(&Asrc[(64 * wm + 16 * m + fr) * 32 + kg]);
            #pragma unroll
            for (int n = 0; n < 2; ++n)
                bb[n] = *reinterpret_cast<const bf16x8*>(&Bsrc[(32 * wn + 16 * n + fr) * 32 + kg]);
            #pragma unroll
            for (int m = 0; m < 4; ++m)
                #pragma unroll
                for (int n = 0; n < 2; ++n)
                    acc[m][n] = __builtin_amdgcn_mfma_f32_16x16x32_bf16(a[m], bb[n], acc[m][n], 0, 0, 0);
        }
        __syncthreads();
    }
    #pragma unroll
    for (int n = 0; n < 2; ++n) {
        int col = bn + 32 * wn + 16 * n + fr;
        float bv = d.bias ? d.bias[col] : 0.f;
        #pragma unroll
        for (int m = 0; m < 4; ++m)
            #pragma unroll
            for (int i = 0; i < 4; ++i) {
                int row = bm + 64 * wm + 16 * m + quad * 4 + i;
                float v = acc[m][n][i] + bv;
                if (d.out_bf16)
                    ((unsigned short*)d.C)[(size_t)row * d.N + col] = f2b(v);
                else
                    ((float*)d.C)[(size_t)row * d.N + col] = v;
            }
    }
}

// ---------------- logits GEMM: BK=64 split-chunk core + fused softmax stats ----------------
__global__ __launch_bounds__(512) void gemm_logits(const unsigned short* __restrict__ A,
                                                   const unsigned short* __restrict__ Bw,
                                                   const float* __restrict__ bias,
                                                   float* __restrict__ Cout,
                                                   float2* __restrict__ stats,
                                                   int M, int N, int K) {
    __shared__ unsigned short As0[128 * 32], As1[128 * 32];
    __shared__ unsigned short Bs0[128 * 32], Bs1[128 * 32];
    __shared__ float mred[128][4];
    __shared__ float sred[128][4];
    const int wg = xcd_swz(blockIdx.x, gridDim.x);
    const int mtiles = M >> 7;
    const int bm = (wg % mtiles) << 7, bn = (wg / mtiles) << 7;
    const int tid = threadIdx.x, lane = tid & 63, w = tid >> 6;
    const int wm = w >> 2, wn = w & 3;
    const int quad = lane >> 4, fr = lane & 15;
    f32x4 acc[4][2] = {};

    const int sr = w * 16 + (lane >> 2), sc = (lane & 3) * 8;
    const unsigned short* agp = A + (size_t)(bm + sr) * K + sc;
    const unsigned short* bgp = Bw + (size_t)(bn + sr) * K + sc;
    unsigned short* a0 = As0 + w * 512;
    unsigned short* a1 = As1 + w * 512;
    unsigned short* b0 = Bs0 + w * 512;
    unsigned short* b1 = Bs1 + w * 512;

    for (int k0 = 0; k0 < K; k0 += 64) {
        gload_lds16(agp + k0, a0);
        gload_lds16(agp + k0 + 32, a1);
        gload_lds16(bgp + k0, b0);
        gload_lds16(bgp + k0 + 32, b1);
        __syncthreads();
        #pragma unroll
        for (int ks = 0; ks < 2; ++ks) {
            const unsigned short* Asrc = ks ? As1 : As0;
            const unsigned short* Bsrc = ks ? Bs1 : Bs0;
            const int kg = quad * 8;
            bf16x8 a[4], bb[2];
            #pragma unroll
            for (int m = 0; m < 4; ++m)
                a[m] = *reinterpret_cast<const bf16x8*>(&Asrc[(64 * wm + 16 * m + fr) * 32 + kg]);
            #pragma unroll
            for (int n = 0; n < 2; ++n)
                bb[n] = *reinterpret_cast<const bf16x8*>(&Bsrc[(32 * wn + 16 * n + fr) * 32 + kg]);
            #pragma unroll
            for (int m = 0; m < 4; ++m)
                #pragma unroll
                for (int n = 0; n < 2; ++n)
                    acc[m][n] = __builtin_amdgcn_mfma_f32_16x16x32_bf16(a[m], bb[n], acc[m][n], 0, 0, 0);
        }
        __syncthreads();
    }

    #pragma unroll
    for (int n = 0; n < 2; ++n) {
        int col = bn + 32 * wn + 16 * n + fr;
        float bv = bias[col];
        #pragma unroll
        for (int m = 0; m < 4; ++m)
            #pragma unroll
            for (int i = 0; i < 4; ++i) {
                int row = bm + 64 * wm + 16 * m + quad * 4 + i;
                float v = acc[m][n][i] + bv;
                Cout[(size_t)row * N + col] = v;
                acc[m][n][i] = v;
            }
    }

    const int nchunk = N >> 7;
    #pragma unroll
    for (int m = 0; m < 4; ++m)
        #pragma unroll
        for (int i = 0; i < 4; ++i) {
            float x = fmaxf(acc[m][0][i], acc[m][1][i]);
            x = fmaxf(x, __shfl_xor(x, 1)); x = fmaxf(x, __shfl_xor(x, 2));
            x = fmaxf(x, __shfl_xor(x, 4)); x = fmaxf(x, __shfl_xor(x, 8));
            if (fr == 0) mred[64 * wm + 16 * m + quad * 4 + i][wn] = x;
        }
    __syncthreads();
    #pragma unroll
    for (int m = 0; m < 4; ++m)
        #pragma unroll
        for (int i = 0; i < 4; ++i) {
            int rl = 64 * wm + 16 * m + quad * 4 + i;
            float Mr = fmaxf(fmaxf(mred[rl][0], mred[rl][1]), fmaxf(mred[rl][2], mred[rl][3]));
            float sv = expf(acc[m][0][i] - Mr) + expf(acc[m][1][i] - Mr);
            sv += __shfl_xor(sv, 1); sv += __shfl_xor(sv, 2);
            sv += __shfl_xor(sv, 4); sv += __shfl_xor(sv, 8);
            if (fr == 0) sred[rl][wn] = sv;
        }
    __syncthreads();
    if (tid < 128) {
        float Mr = fmaxf(fmaxf(mred[tid][0], mred[tid][1]), fmaxf(mred[tid][2], mred[tid][3]));
        float Sv = sred[tid][0] + sred[tid][1] + sred[tid][2] + sred[tid][3];
        stats[(size_t)(bm + tid) * nchunk + (bn >> 7)] = make_float2(Mr, Sv);
    }
}

// ---------------- phase A: 64x32 tile, BK=128, grid 128, 256 thr (R11 verbatim) ----------------
__global__ __launch_bounds__(256) void gemm_smallA(const unsigned short* __restrict__ A,
                                                   const unsigned short* __restrict__ Bw,
                                                   const float* __restrict__ bias,
                                                   float* __restrict__ Cout) {
    __shared__ unsigned short As[64][136];
    __shared__ unsigned short Bs[32][136];
    const int bn = blockIdx.x * 32;
    const int tid = threadIdx.x, lane = tid & 63, w = tid >> 6;
    const int quad = lane >> 4, fr = lane & 15;
    f32x4 acc[2] = {};

    const int srA = tid >> 2, scA = (tid & 3) * 32;
    const int srB = tid >> 3, scB = (tid & 7) * 16;
    for (int k0 = 0; k0 < H; k0 += 128) {
        const unsigned short* ap = A + (size_t)srA * H + k0 + scA;
        #pragma unroll
        for (int u = 0; u < 4; ++u)
            *reinterpret_cast<bf16x8*>(&As[srA][scA + 8 * u]) =
                *reinterpret_cast<const bf16x8*>(ap + 8 * u);
        const unsigned short* bp = Bw + (size_t)(bn + srB) * H + k0 + scB;
        *reinterpret_cast<bf16x8*>(&Bs[srB][scB])     = *reinterpret_cast<const bf16x8*>(bp);
        *reinterpret_cast<bf16x8*>(&Bs[srB][scB + 8]) = *reinterpret_cast<const bf16x8*>(bp + 8);
        __syncthreads();
        #pragma unroll
        for (int ks = 0; ks < 4; ++ks) {
            const int kg = quad * 8 + 32 * ks;
            bf16x8 a = *reinterpret_cast<const bf16x8*>(&As[16 * w + fr][kg]);
            #pragma unroll
            for (int n = 0; n < 2; ++n) {
                bf16x8 bb = *reinterpret_cast<const bf16x8*>(&Bs[16 * n + fr][kg]);
                acc[n] = __builtin_amdgcn_mfma_f32_16x16x32_bf16(a, bb, acc[n], 0, 0, 0);
            }
        }
        __syncthreads();
    }
    #pragma unroll
    for (int n = 0; n < 2; ++n) {
        int col = bn + 16 * n + fr;
        float bv = bias[col];
        #pragma unroll
        for (int i = 0; i < 4; ++i) {
            int row = 16 * w + quad * 4 + i;
            Cout[(size_t)row * 4096 + col] = acc[n][i] + bv;
        }
    }
}

// ---------------- phase B: step work (blocks 0-255) + out_w conv filler (blocks 256+) ----------------
__global__ __launch_bounds__(256) void stepB(const float* __restrict__ ghq,
                                             const unsigned short* __restrict__ keys,
                                             const unsigned short* __restrict__ KV,
                                             const float* __restrict__ va,
                                             const float* __restrict__ va_b,
                                             const float* __restrict__ gi_emb,
                                             float* __restrict__ h,
                                             unsigned short* __restrict__ hbf,
                                             unsigned short* __restrict__ outs_bf,
                                             float* __restrict__ attns,
                                             float* __restrict__ h_final,
                                             const float* __restrict__ out_w,
                                             unsigned short* __restrict__ outw_bf, int t) {
    const int bid = blockIdx.x;
    const int tid = threadIdx.x, lane = tid & 63, wv = tid >> 6;
    __shared__ float ssc[128];
    __shared__ float sw[128];
    __shared__ float red[4][64][13];

    if (bid >= 256) {
        // out_w conversion filler: launch t handles f4 range [t*819200, (t+1)*819200)
        size_t base = (size_t)t * (CONV_BLKS * 1024) + (size_t)(bid - 256) * 1024;
        #pragma unroll
        for (int k = 0; k < 4; ++k) {
            size_t i = base + k * 256 + tid;
            float4 v = reinterpret_cast<const float4*>(out_w)[i];
            ushort4 o = { f2b(v.x), f2b(v.y), f2b(v.z), f2b(v.w) };
            reinterpret_cast<ushort4*>(outw_bf)[i] = o;
        }
        return;
    }

    const int q = bid & 3, b = bid >> 2;
    float qv[16], vv[16];
    {
        const float* qp = ghq + (size_t)b * 4096 + H3 + lane * 16;
        const float* vp = va + lane * 16;
        #pragma unroll
        for (int j = 0; j < 16; ++j) { qv[j] = qp[j]; vv[j] = vp[j]; }
    }
    const float vab = va_b[0];
    const unsigned short* kb = keys + (size_t)b * S * H;
    for (int i = 0; i < 32; i += 2) {
        int s0 = wv * 32 + i;
        const unsigned short* kr0 = kb + (size_t)s0 * H + lane * 16;
        const unsigned short* kr1 = kr0 + H;
        ushort8v k00 = *reinterpret_cast<const ushort8v*>(kr0);
        ushort8v k01 = *reinterpret_cast<const ushort8v*>(kr0 + 8);
        ushort8v k10 = *reinterpret_cast<const ushort8v*>(kr1);
        ushort8v k11 = *reinterpret_cast<const ushort8v*>(kr1 + 8);
        float a0 = 0.f, a1 = 0.f;
        #pragma unroll
        for (int e = 0; e < 8; ++e) {
            a0 += fast_tanh(qv[e] + b2f(k00[e])) * vv[e];
            a1 += fast_tanh(qv[e] + b2f(k10[e])) * vv[e];
        }
        #pragma unroll
        for (int e = 0; e < 8; ++e) {
            a0 += fast_tanh(qv[8 + e] + b2f(k01[e])) * vv[8 + e];
            a1 += fast_tanh(qv[8 + e] + b2f(k11[e])) * vv[8 + e];
        }
        a0 += __shfl_xor(a0, 1);  a1 += __shfl_xor(a1, 1);
        a0 += __shfl_xor(a0, 2);  a1 += __shfl_xor(a1, 2);
        a0 += __shfl_xor(a0, 4);  a1 += __shfl_xor(a1, 4);
        a0 += __shfl_xor(a0, 8);  a1 += __shfl_xor(a1, 8);
        a0 += __shfl_xor(a0, 16); a1 += __shfl_xor(a1, 16);
        a0 += __shfl_xor(a0, 32); a1 += __shfl_xor(a1, 32);
        if (lane == 0) { ssc[s0] = a0 + vab; ssc[s0 + 1] = a1 + vab; }
    }
    __syncthreads();
    if (tid < 128) {
        float mx = -1e30f;
        #pragma unroll 8
        for (int s = 0; s < 128; ++s) mx = fmaxf(mx, ssc[s]);
        float sum = 0.f;
        #pragma unroll 8
        for (int s = 0; s < 128; ++s) sum += __expf(ssc[s] - mx);
        float wvv = __expf(ssc[tid] - mx) / sum;
        sw[tid] = wvv;
        if (q == 0) attns[((size_t)b * T + t) * S + tid] = wvv;
    }
    __syncthreads();

    const int j0 = q * 256 + lane * 4;
    float ar[4] = {}, az[4] = {}, an[4] = {};
    const unsigned short* kvb = KV + (size_t)b * S * H3 + j0;
    for (int i = 0; i < 32; i += 2) {
        int s0 = wv * 32 + i;
        float w0 = sw[s0], w1 = sw[s0 + 1];
        const unsigned short* r0 = kvb + (size_t)s0 * H3;
        const unsigned short* r1 = r0 + H3;
        uint2 u0a = *reinterpret_cast<const uint2*>(r0);
        uint2 u1a = *reinterpret_cast<const uint2*>(r0 + 1024);
        uint2 u2a = *reinterpret_cast<const uint2*>(r0 + 2048);
        uint2 u0b = *reinterpret_cast<const uint2*>(r1);
        uint2 u1b = *reinterpret_cast<const uint2*>(r1 + 1024);
        uint2 u2b = *reinterpret_cast<const uint2*>(r1 + 2048);
        ar[0] += w0 * b2f((unsigned short)(u0a.x & 0xffff)) + w1 * b2f((unsigned short)(u0b.x & 0xffff));
        ar[1] += w0 * b2f((unsigned short)(u0a.x >> 16))    + w1 * b2f((unsigned short)(u0b.x >> 16));
        ar[2] += w0 * b2f((unsigned short)(u0a.y & 0xffff)) + w1 * b2f((unsigned short)(u0b.y & 0xffff));
        ar[3] += w0 * b2f((unsigned short)(u0a.y >> 16))    + w1 * b2f((unsigned short)(u0b.y >> 16));
        az[0] += w0 * b2f((unsigned short)(u1a.x & 0xffff)) + w1 * b2f((unsigned short)(u1b.x & 0xffff));
        az[1] += w0 * b2f((unsigned short)(u1a.x >> 16))    + w1 * b2f((unsigned short)(u1b.x >> 16));
        az[2] += w0 * b2f((unsigned short)(u1a.y & 0xffff)) + w1 * b2f((unsigned short)(u1b.y & 0xffff));
        az[3] += w0 * b2f((unsigned short)(u1a.y >> 16))    + w1 * b2f((unsigned short)(u1b.y >> 16));
        an[0] += w0 * b2f((unsigned short)(u2a.x & 0xffff)) + w1 * b2f((unsigned short)(u2b.x & 0xffff));
        an[1] += w0 * b2f((unsigned short)(u2a.x >> 16))    + w1 * b2f((unsigned short)(u2b.x >> 16));
        an[2] += w0 * b2f((unsigned short)(u2a.y & 0xffff)) + w1 * b2f((unsigned short)(u2b.y & 0xffff));
        an[3] += w0 * b2f((unsigned short)(u2a.y >> 16))    + w1 * b2f((unsigned short)(u2b.y >> 16));
    }
    #pragma unroll
    for (int g = 0; g < 4; ++g) {
        red[wv][lane][g]     = ar[g];
        red[wv][lane][4 + g] = az[g];
        red[wv][lane][8 + g] = an[g];
    }
    __syncthreads();

    if (tid < 64) {
        float rr[4], zz[4], nn[4];
        #pragma unroll
        for (int g = 0; g < 4; ++g) {
            rr[g] = red[0][tid][g] + red[1][tid][g] + red[2][tid][g] + red[3][tid][g];
            zz[g] = red[0][tid][4+g] + red[1][tid][4+g] + red[2][tid][4+g] + red[3][tid][4+g];
            nn[g] = red[0][tid][8+g] + red[1][tid][8+g] + red[2][tid][8+g] + red[3][tid][8+g];
        }
        const int jj = q * 256 + tid * 4;
        const float* ge = gi_emb + ((size_t)t * B + b) * H3;
        const float* gh = ghq + (size_t)b * 4096;
        float geR[4], geZ[4], geN[4], ghR[4], ghZ[4], ghN[4], hv[4];
        *reinterpret_cast<float4*>(geR) = *reinterpret_cast<const float4*>(ge + jj);
        *reinterpret_cast<float4*>(geZ) = *reinterpret_cast<const float4*>(ge + 1024 + jj);
        *reinterpret_cast<float4*>(geN) = *reinterpret_cast<const float4*>(ge + 2048 + jj);
        *reinterpret_cast<float4*>(ghR) = *reinterpret_cast<const float4*>(gh + jj);
        *reinterpret_cast<float4*>(ghZ) = *reinterpret_cast<const float4*>(gh + 1024 + jj);
        *reinterpret_cast<float4*>(ghN) = *reinterpret_cast<const float4*>(gh + 2048 + jj);
        *reinterpret_cast<float4*>(hv)  = *reinterpret_cast<const float4*>(h + (size_t)b * H + jj);
        ushort4 hb;
        unsigned short* hbp = reinterpret_cast<unsigned short*>(&hb);
        #pragma unroll
        for (int i = 0; i < 4; ++i) {
            float r = fast_sigmoid(geR[i] + rr[i] + ghR[i]);
            float z = fast_sigmoid(geZ[i] + zz[i] + ghZ[i]);
            float n = fast_tanh(geN[i] + nn[i] + r * ghN[i]);
            hv[i] = (1.f - z) * n + z * hv[i];
            hbp[i] = f2b(hv[i]);
        }
        *reinterpret_cast<float4*>(h + (size_t)b * H + jj) = *reinterpret_cast<float4*>(hv);
        *reinterpret_cast<ushort4*>(hbf + (size_t)b * H + jj) = hb;
        *reinterpret_cast<ushort4*>(outs_bf + ((size_t)b * T + t) * H + jj) = hb;
        if (t == T - 1)
            *reinterpret_cast<float4*>(h_final + (size_t)b * H + jj) = *reinterpret_cast<float4*>(hv);
    }
}

// ---------------- fused LSE + subtract ----------------
__global__ void lsesub_kernel(const float2* __restrict__ stats, float* __restrict__ x) {
    const int row = blockIdx.x;
    const int tid = threadIdx.x;
    __shared__ float shm[256];
    __shared__ float shs[256];
    float mv = -1e30f, sv = 0.f;
    float2 st = make_float2(-1e30f, 0.f);
    if (tid < NCHUNK) { st = stats[(size_t)row * NCHUNK + tid]; mv = st.x; }
    shm[tid] = mv; __syncthreads();
    for (int off = 128; off > 0; off >>= 1) {
        if (tid < off) shm[tid] = fmaxf(shm[tid], shm[tid + off]);
        __syncthreads();
    }
    float M = shm[0]; __syncthreads();
    if (tid < NCHUNK) sv = st.y * expf(st.x - M);
    shs[tid] = sv; __syncthreads();
    for (int off = 128; off > 0; off >>= 1) {
        if (tid < off) shs[tid] += shs[tid + off];
        __syncthreads();
    }
    float L = M + logf(shs[0]);
    __syncthreads();
    float4* p = reinterpret_cast<float4*>(x + (size_t)row * V);
    for (int i = tid; i < V / 4; i += 256) {
        float4 v = p[i];
        v.x -= L; v.y -= L; v.z -= L; v.w -= L;
        p[i] = v;
    }
}

// ---------------- host ----------------

extern "C" void kernel_launch(void* const* d_in, const int* in_sizes, int n_in,
                              void* d_out, int out_size, void* d_ws, size_t ws_size,
                              hipStream_t stream) {
    const float* enc   = (const float*)d_in[0];
    const float* h0    = (const float*)d_in[1];
    const int*   tgt   = (const int*)d_in[2];
    const float* emb   = (const float*)d_in[3];
    const float* Wa_w  = (const float*)d_in[4];
    const float* Wa_b  = (const float*)d_in[5];
    const float* Ua_w  = (const float*)d_in[6];
    const float* Ua_b  = (const float*)d_in[7];
    const float* Va_w  = (const float*)d_in[8];
    const float* Va_b  = (const float*)d_in[9];
    const float* gwi   = (const float*)d_in[10];
    const float* gwh   = (const float*)d_in[11];
    const float* gbi   = (const float*)d_in[12];
    const float* gbh   = (const float*)d_in[13];
    const float* out_w = (const float*)d_in[14];
    const float* out_b = (const float*)d_in[15];

    float* out       = (float*)d_out;
    float* log_probs = out;                          // [B*T, V]
    float* h_final   = out + (size_t)B * T * V;      // [B, H]
    float* attns     = h_final + (size_t)B * H;      // [B, T, S]

    char* pp = (char*)d_ws;
    auto alloc = [&](size_t bytes) { char* r = pp; pp += (bytes + 255) & ~(size_t)255; return r; };
    unsigned short* ua_bf   = (unsigned short*)alloc((size_t)B * S * H * 2);
    unsigned short* enc_bf  = (unsigned short*)alloc((size_t)B * S * H * 2);
    unsigned short* outw_bf = (unsigned short*)alloc((size_t)V * H * 2);
    unsigned short* KV      = (unsigned short*)alloc((size_t)B * S * H3 * 2);
    unsigned short* Ua_bf   = (unsigned short*)alloc((size_t)H * H * 2);
    unsigned short* Wcat    = (unsigned short*)alloc((size_t)4096 * H * 2);
    unsigned short* Wctx    = (unsigned short*)alloc((size_t)H3 * H * 2);
    unsigned short* Wemb    = (unsigned short*)alloc((size_t)H3 * H * 2);
    float*          catbias = (float*)alloc(4096 * 4);
    unsigned short* embg    = (unsigned short*)alloc((size_t)T * B * H * 2);
    float*          gi_emb  = (float*)alloc((size_t)T * B * H3 * 4);
    float*          hbuf    = (float*)alloc((size_t)B * H * 4);
    unsigned short* hbf     = (unsigned short*)alloc((size_t)B * H * 2);
    float*          ghq     = (float*)alloc((size_t)B * 4096 * 4);
    unsigned short* outs_bf = (unsigned short*)alloc((size_t)B * T * H * 2);
    float2*         stats   = (float2*)alloc((size_t)B * T * NCHUNK * 8);

    prep_kernel<<<PREP_NB, 256, 0, stream>>>(enc, enc_bf, Ua_w, Ua_bf,
                                             gwh, Wa_w, Wcat, gwi, Wemb, Wctx,
                                             gbh, Wa_b, catbias, emb, tgt, embg,
                                             h0, hbf, hbuf);

    GemmDesc d0 = { enc_bf, Ua_bf, Ua_b, (void*)ua_bf,  B * S, H,  1 };
    GemmDesc d1 = { enc_bf, Wctx,  nullptr, (void*)KV,  B * S, H3, 1 };
    GemmDesc d2 = { embg,   Wemb,  gbi, (void*)gi_emb,  T * B, H3, 0 };
    gemm3_kernel<<<2168, 512, 0, stream>>>(d0, d1, d2);

    for (int t = 0; t < T; ++t) {
        gemm_smallA<<<128, 256, 0, stream>>>(hbf, Wcat, catbias, ghq);
        stepB<<<256 + CONV_BLKS, 256, 0, stream>>>(ghq, ua_bf, KV, Va_w, Va_b, gi_emb,
                                                   hbuf, hbf, outs_bf, attns, h_final,
                                                   out_w, outw_bf, t);
    }

    gemm_logits<<<(B * T / 128) * (V / 128), 512, 0, stream>>>(
        outs_bf, outw_bf, out_b, log_probs, stats, B * T, V, H);
    lsesub_kernel<<<B * T, 256, 0, stream>>>(stats, log_probs);
}

// Round 17
// 686.574 us; speedup vs baseline: 1.1778x; 1.0168x over previous
//
#include <hip/hip_runtime.h>
#include <hip/hip_bf16.h>
#include <cstddef>

#define B 64
#define S 128
#define H 1024
#define V 32000
#define T 10
#define H3 3072
#define NCHUNK 250
#define CONV_BLKS 800     // per stepB launch; 800*1024 f4 * 10 launches = V*H/4

typedef __bf16 bf16x8 __attribute__((ext_vector_type(8)));
typedef float f32x4 __attribute__((ext_vector_type(4)));
typedef unsigned short ushort8v __attribute__((ext_vector_type(8)));

__device__ inline unsigned short f2b(float f) {
    __hip_bfloat16 h = __float2bfloat16(f);
    return *reinterpret_cast<unsigned short*>(&h);
}
__device__ inline float b2f(unsigned short u) {
    return __uint_as_float(((unsigned)u) << 16);
}
__device__ inline float fast_tanh(float x) {
    float e = __expf(2.f * x);
    return 1.f - 2.f * __builtin_amdgcn_rcpf(e + 1.f);
}
__device__ inline float fast_sigmoid(float x) {
    return __builtin_amdgcn_rcpf(1.f + __expf(-x));
}

// async global->LDS, 16B per lane
__device__ inline void gload_lds16(const void* g, void* l) {
    __builtin_amdgcn_global_load_lds(
        (const __attribute__((address_space(1))) void*)g,
        (__attribute__((address_space(3))) void*)l, 16, 0, 0);
}

// bijective XCD swizzle (m204)
__device__ inline int xcd_swz(int orig, int nwg) {
    int q = nwg >> 3, r = nwg & 7;
    int xcd = orig & 7, idx = orig >> 3;
    int base = (xcd < r) ? xcd * (q + 1) : r * (q + 1) + (xcd - r) * q;
    return base + idx;
}

// ---------------- prep kernel (R11 verbatim) ----------------
#define PREP_NB 20240
__global__ void prep_kernel(const float* __restrict__ enc, unsigned short* __restrict__ enc_bf,
                            const float* __restrict__ Ua_w, unsigned short* __restrict__ Ua_bf,
                            const float* __restrict__ gwh, const float* __restrict__ Wa_w,
                            unsigned short* __restrict__ Wcat,
                            const float* __restrict__ gwi,
                            unsigned short* __restrict__ Wemb, unsigned short* __restrict__ Wctx,
                            const float* __restrict__ gbh, const float* __restrict__ Wa_b,
                            float* __restrict__ catbias,
                            const float* __restrict__ emb, const int* __restrict__ tgt,
                            unsigned short* __restrict__ embg,
                            const float* __restrict__ h0, unsigned short* __restrict__ hbf,
                            float* __restrict__ hbuf) {
    const int bid = blockIdx.x, tid = threadIdx.x;
    if (bid < 8192) {
        int i = bid * 256 + tid;
        float4 v = reinterpret_cast<const float4*>(enc)[i];
        ushort4 o = { f2b(v.x), f2b(v.y), f2b(v.z), f2b(v.w) };
        reinterpret_cast<ushort4*>(enc_bf)[i] = o;
    } else if (bid < 9216) {
        int i = (bid - 8192) * 256 + tid;
        float4 v = reinterpret_cast<const float4*>(Ua_w)[i];
        ushort4 o = { f2b(v.x), f2b(v.y), f2b(v.z), f2b(v.w) };
        reinterpret_cast<ushort4*>(Ua_bf)[i] = o;
    } else if (bid < 13312) {
        int i = (bid - 9216) * 256 + tid;
        int e = i * 4, n = e >> 10, k = e & 1023;
        const float* src = (n < H3) ? (gwh + (size_t)n * H + k) : (Wa_w + (size_t)(n - H3) * H + k);
        float4 v = *reinterpret_cast<const float4*>(src);
        ushort4 o = { f2b(v.x), f2b(v.y), f2b(v.z), f2b(v.w) };
        reinterpret_cast<ushort4*>(Wcat)[i] = o;
    } else if (bid < 16384) {
        int i = (bid - 13312) * 256 + tid;
        int e = i * 4, n = e >> 10, k = e & 1023;
        float4 v = *reinterpret_cast<const float4*>(gwi + (size_t)n * 2 * H + k);
        ushort4 o = { f2b(v.x), f2b(v.y), f2b(v.z), f2b(v.w) };
        reinterpret_cast<ushort4*>(Wemb)[i] = o;
    } else if (bid < 19456) {
        int i = (bid - 16384) * 256 + tid;
        int e = i * 4, n = e >> 10, k = e & 1023;
        float4 v = *reinterpret_cast<const float4*>(gwi + (size_t)n * 2 * H + H + k);
        ushort4 o = { f2b(v.x), f2b(v.y), f2b(v.z), f2b(v.w) };
        reinterpret_cast<ushort4*>(Wctx)[i] = o;
    } else if (bid < 19472) {
        int n = (bid - 19456) * 256 + tid;
        catbias[n] = (n < H3) ? gbh[n] : Wa_b[n - H3];
    } else if (bid < 20112) {
        int i = (bid - 19472) * 256 + tid;
        int e = i * 4;
        int t = e >> 16, rem = e & 65535;
        int b = rem >> 10, j = rem & 1023;
        int tok = (t == 0) ? 0 : tgt[b * T + (t - 1)];
        float4 v = *reinterpret_cast<const float4*>(emb + (size_t)tok * H + j);
        ushort4 o = { f2b(v.x), f2b(v.y), f2b(v.z), f2b(v.w) };
        *reinterpret_cast<ushort4*>(embg + ((size_t)t * B + b) * H + j) = o;
    } else if (bid < 20176) {
        int i = (bid - 20112) * 256 + tid;
        float4 v = reinterpret_cast<const float4*>(h0)[i];
        ushort4 o = { f2b(v.x), f2b(v.y), f2b(v.z), f2b(v.w) };
        reinterpret_cast<ushort4*>(hbf)[i] = o;
    } else {
        int i = (bid - 20176) * 256 + tid;
        reinterpret_cast<float4*>(hbuf)[i] = reinterpret_cast<const float4*>(h0)[i];
    }
}

// ---------------- merged 3-GEMM; BK=64 split-chunk gload_lds core (R16 verbatim) ----------------
struct GemmDesc {
    const unsigned short* A;
    const unsigned short* Bw;
    const float* bias;
    void* C;
    int M, N, out_bf16;
};

// blocks [0,512) d0 | [512,2048) d1 | [2048,2168) d2
__global__ __launch_bounds__(512) void gemm3_kernel(GemmDesc d0, GemmDesc d1, GemmDesc d2) {
    __shared__ unsigned short As0[128 * 32], As1[128 * 32];
    __shared__ unsigned short Bs0[128 * 32], Bs1[128 * 32];
    const int bid = blockIdx.x;
    const int tid = threadIdx.x;
    GemmDesc d; int local, nwg;
    if (bid < 512)       { d = d0; local = bid;        nwg = 512;  }
    else if (bid < 2048) { d = d1; local = bid - 512;  nwg = 1536; }
    else                 { d = d2; local = bid - 2048; nwg = 120;  }
    local = xcd_swz(local, nwg);
    const int mtiles = d.M >> 7;
    const int bm = (local % mtiles) << 7, bn = (local / mtiles) << 7;
    const int lane = tid & 63, w = tid >> 6;
    const int wm = w >> 2, wn = w & 3;
    const int quad = lane >> 4, fr = lane & 15;
    const int K = H;
    f32x4 acc[4][2] = {};

    const int sr = w * 16 + (lane >> 2), sc = (lane & 3) * 8;
    const unsigned short* agp = d.A + (size_t)(bm + sr) * K + sc;
    const unsigned short* bgp = d.Bw + (size_t)(bn + sr) * K + sc;
    unsigned short* a0 = As0 + w * 512;
    unsigned short* a1 = As1 + w * 512;
    unsigned short* b0 = Bs0 + w * 512;
    unsigned short* b1 = Bs1 + w * 512;

    for (int k0 = 0; k0 < K; k0 += 64) {
        gload_lds16(agp + k0, a0);
        gload_lds16(agp + k0 + 32, a1);
        gload_lds16(bgp + k0, b0);
        gload_lds16(bgp + k0 + 32, b1);
        __syncthreads();
        #pragma unroll
        for (int ks = 0; ks < 2; ++ks) {
            const unsigned short* Asrc = ks ? As1 : As0;
            const unsigned short* Bsrc = ks ? Bs1 : Bs0;
            const int kg = quad * 8;
            bf16x8 a[4], bb[2];
            #pragma unroll
            for (int m = 0; m < 4; ++m)
                a[m] = *reinterpret_cast<const bf16x8*>(&Asrc[(64 * wm + 16 * m + fr) * 32 + kg]);
            #pragma unroll
            for (int n = 0; n < 2; ++n)
                bb[n] = *reinterpret_cast<const bf16x8*>(&Bsrc[(32 * wn + 16 * n + fr) * 32 + kg]);
            #pragma unroll
            for (int m = 0; m < 4; ++m)
                #pragma unroll
                for (int n = 0; n < 2; ++n)
                    acc[m][n] = __builtin_amdgcn_mfma_f32_16x16x32_bf16(a[m], bb[n], acc[m][n], 0, 0, 0);
        }
        __syncthreads();
    }
    #pragma unroll
    for (int n = 0; n < 2; ++n) {
        int col = bn + 32 * wn + 16 * n + fr;
        float bv = d.bias ? d.bias[col] : 0.f;
        #pragma unroll
        for (int m = 0; m < 4; ++m)
            #pragma unroll
            for (int i = 0; i < 4; ++i) {
                int row = bm + 64 * wm + 16 * m + quad * 4 + i;
                float v = acc[m][n][i] + bv;
                if (d.out_bf16)
                    ((unsigned short*)d.C)[(size_t)row * d.N + col] = f2b(v);
                else
                    ((float*)d.C)[(size_t)row * d.N + col] = v;
            }
    }
}

// ---------------- logits GEMM: BK=32 m97-style core (R11 verbatim) + fused softmax stats ----------------
__global__ __launch_bounds__(512) void gemm_logits(const unsigned short* __restrict__ A,
                                                   const unsigned short* __restrict__ Bw,
                                                   const float* __restrict__ bias,
                                                   float* __restrict__ Cout,
                                                   float2* __restrict__ stats,
                                                   int M, int N, int K) {
    __shared__ unsigned short As[128 * 32];
    __shared__ unsigned short Bs[128 * 32];
    __shared__ float mred[128][4];
    __shared__ float sred[128][4];
    const int wg = xcd_swz(blockIdx.x, gridDim.x);
    const int mtiles = M >> 7;
    const int bm = (wg % mtiles) << 7, bn = (wg / mtiles) << 7;
    const int tid = threadIdx.x, lane = tid & 63, w = tid >> 6;
    const int wm = w >> 2, wn = w & 3;
    const int quad = lane >> 4, fr = lane & 15;
    f32x4 acc[4][2] = {};

    const int sr = w * 16 + (lane >> 2), sc = (lane & 3) * 8;
    const unsigned short* agp = A + (size_t)(bm + sr) * K + sc;
    const unsigned short* bgp = Bw + (size_t)(bn + sr) * K + sc;
    unsigned short* alp = As + w * 512;
    unsigned short* blp = Bs + w * 512;

    for (int k0 = 0; k0 < K; k0 += 32) {
        gload_lds16(agp + k0, alp);
        gload_lds16(bgp + k0, blp);
        __syncthreads();
        const int kg = quad * 8;
        bf16x8 a[4], bb[2];
        #pragma unroll
        for (int m = 0; m < 4; ++m)
            a[m] = *reinterpret_cast<const bf16x8*>(&As[(64 * wm + 16 * m + fr) * 32 + kg]);
        #pragma unroll
        for (int n = 0; n < 2; ++n)
            bb[n] = *reinterpret_cast<const bf16x8*>(&Bs[(32 * wn + 16 * n + fr) * 32 + kg]);
        #pragma unroll
        for (int m = 0; m < 4; ++m)
            #pragma unroll
            for (int n = 0; n < 2; ++n)
                acc[m][n] = __builtin_amdgcn_mfma_f32_16x16x32_bf16(a[m], bb[n], acc[m][n], 0, 0, 0);
        __syncthreads();
    }

    #pragma unroll
    for (int n = 0; n < 2; ++n) {
        int col = bn + 32 * wn + 16 * n + fr;
        float bv = bias[col];
        #pragma unroll
        for (int m = 0; m < 4; ++m)
            #pragma unroll
            for (int i = 0; i < 4; ++i) {
                int row = bm + 64 * wm + 16 * m + quad * 4 + i;
                float v = acc[m][n][i] + bv;
                Cout[(size_t)row * N + col] = v;
                acc[m][n][i] = v;
            }
    }

    const int nchunk = N >> 7;
    #pragma unroll
    for (int m = 0; m < 4; ++m)
        #pragma unroll
        for (int i = 0; i < 4; ++i) {
            float x = fmaxf(acc[m][0][i], acc[m][1][i]);
            x = fmaxf(x, __shfl_xor(x, 1)); x = fmaxf(x, __shfl_xor(x, 2));
            x = fmaxf(x, __shfl_xor(x, 4)); x = fmaxf(x, __shfl_xor(x, 8));
            if (fr == 0) mred[64 * wm + 16 * m + quad * 4 + i][wn] = x;
        }
    __syncthreads();
    #pragma unroll
    for (int m = 0; m < 4; ++m)
        #pragma unroll
        for (int i = 0; i < 4; ++i) {
            int rl = 64 * wm + 16 * m + quad * 4 + i;
            float Mr = fmaxf(fmaxf(mred[rl][0], mred[rl][1]), fmaxf(mred[rl][2], mred[rl][3]));
            float sv = expf(acc[m][0][i] - Mr) + expf(acc[m][1][i] - Mr);
            sv += __shfl_xor(sv, 1); sv += __shfl_xor(sv, 2);
            sv += __shfl_xor(sv, 4); sv += __shfl_xor(sv, 8);
            if (fr == 0) sred[rl][wn] = sv;
        }
    __syncthreads();
    if (tid < 128) {
        float Mr = fmaxf(fmaxf(mred[tid][0], mred[tid][1]), fmaxf(mred[tid][2], mred[tid][3]));
        float Sv = sred[tid][0] + sred[tid][1] + sred[tid][2] + sred[tid][3];
        stats[(size_t)(bm + tid) * nchunk + (bn >> 7)] = make_float2(Mr, Sv);
    }
}

// ---------------- phase A: 64x32 tile, BK=128, grid 128, 256 thr (R11 verbatim) ----------------
__global__ __launch_bounds__(256) void gemm_smallA(const unsigned short* __restrict__ A,
                                                   const unsigned short* __restrict__ Bw,
                                                   const float* __restrict__ bias,
                                                   float* __restrict__ Cout) {
    __shared__ unsigned short As[64][136];
    __shared__ unsigned short Bs[32][136];
    const int bn = blockIdx.x * 32;
    const int tid = threadIdx.x, lane = tid & 63, w = tid >> 6;
    const int quad = lane >> 4, fr = lane & 15;
    f32x4 acc[2] = {};

    const int srA = tid >> 2, scA = (tid & 3) * 32;
    const int srB = tid >> 3, scB = (tid & 7) * 16;
    for (int k0 = 0; k0 < H; k0 += 128) {
        const unsigned short* ap = A + (size_t)srA * H + k0 + scA;
        #pragma unroll
        for (int u = 0; u < 4; ++u)
            *reinterpret_cast<bf16x8*>(&As[srA][scA + 8 * u]) =
                *reinterpret_cast<const bf16x8*>(ap + 8 * u);
        const unsigned short* bp = Bw + (size_t)(bn + srB) * H + k0 + scB;
        *reinterpret_cast<bf16x8*>(&Bs[srB][scB])     = *reinterpret_cast<const bf16x8*>(bp);
        *reinterpret_cast<bf16x8*>(&Bs[srB][scB + 8]) = *reinterpret_cast<const bf16x8*>(bp + 8);
        __syncthreads();
        #pragma unroll
        for (int ks = 0; ks < 4; ++ks) {
            const int kg = quad * 8 + 32 * ks;
            bf16x8 a = *reinterpret_cast<const bf16x8*>(&As[16 * w + fr][kg]);
            #pragma unroll
            for (int n = 0; n < 2; ++n) {
                bf16x8 bb = *reinterpret_cast<const bf16x8*>(&Bs[16 * n + fr][kg]);
                acc[n] = __builtin_amdgcn_mfma_f32_16x16x32_bf16(a, bb, acc[n], 0, 0, 0);
            }
        }
        __syncthreads();
    }
    #pragma unroll
    for (int n = 0; n < 2; ++n) {
        int col = bn + 16 * n + fr;
        float bv = bias[col];
        #pragma unroll
        for (int i = 0; i < 4; ++i) {
            int row = 16 * w + quad * 4 + i;
            Cout[(size_t)row * 4096 + col] = acc[n][i] + bv;
        }
    }
}

// ---------------- phase B: step work (blocks 0-255) + out_w conv filler (blocks 256+) ----------------
__global__ __launch_bounds__(256) void stepB(const float* __restrict__ ghq,
                                             const unsigned short* __restrict__ keys,
                                             const unsigned short* __restrict__ KV,
                                             const float* __restrict__ va,
                                             const float* __restrict__ va_b,
                                             const float* __restrict__ gi_emb,
                                             float* __restrict__ h,
                                             unsigned short* __restrict__ hbf,
                                             unsigned short* __restrict__ outs_bf,
                                             float* __restrict__ attns,
                                             float* __restrict__ h_final,
                                             const float* __restrict__ out_w,
                                             unsigned short* __restrict__ outw_bf, int t) {
    const int bid = blockIdx.x;
    const int tid = threadIdx.x, lane = tid & 63, wv = tid >> 6;
    __shared__ float ssc[128];
    __shared__ float sw[128];
    __shared__ float red[4][64][13];

    if (bid >= 256) {
        size_t base = (size_t)t * (CONV_BLKS * 1024) + (size_t)(bid - 256) * 1024;
        #pragma unroll
        for (int k = 0; k < 4; ++k) {
            size_t i = base + k * 256 + tid;
            float4 v = reinterpret_cast<const float4*>(out_w)[i];
            ushort4 o = { f2b(v.x), f2b(v.y), f2b(v.z), f2b(v.w) };
            reinterpret_cast<ushort4*>(outw_bf)[i] = o;
        }
        return;
    }

    const int q = bid & 3, b = bid >> 2;
    float qv[16], vv[16];
    {
        const float* qp = ghq + (size_t)b * 4096 + H3 + lane * 16;
        const float* vp = va + lane * 16;
        #pragma unroll
        for (int j = 0; j < 16; ++j) { qv[j] = qp[j]; vv[j] = vp[j]; }
    }
    const float vab = va_b[0];
    const unsigned short* kb = keys + (size_t)b * S * H;
    for (int i = 0; i < 32; i += 2) {
        int s0 = wv * 32 + i;
        const unsigned short* kr0 = kb + (size_t)s0 * H + lane * 16;
        const unsigned short* kr1 = kr0 + H;
        ushort8v k00 = *reinterpret_cast<const ushort8v*>(kr0);
        ushort8v k01 = *reinterpret_cast<const ushort8v*>(kr0 + 8);
        ushort8v k10 = *reinterpret_cast<const ushort8v*>(kr1);
        ushort8v k11 = *reinterpret_cast<const ushort8v*>(kr1 + 8);
        float a0 = 0.f, a1 = 0.f;
        #pragma unroll
        for (int e = 0; e < 8; ++e) {
            a0 += fast_tanh(qv[e] + b2f(k00[e])) * vv[e];
            a1 += fast_tanh(qv[e] + b2f(k10[e])) * vv[e];
        }
        #pragma unroll
        for (int e = 0; e < 8; ++e) {
            a0 += fast_tanh(qv[8 + e] + b2f(k01[e])) * vv[8 + e];
            a1 += fast_tanh(qv[8 + e] + b2f(k11[e])) * vv[8 + e];
        }
        a0 += __shfl_xor(a0, 1);  a1 += __shfl_xor(a1, 1);
        a0 += __shfl_xor(a0, 2);  a1 += __shfl_xor(a1, 2);
        a0 += __shfl_xor(a0, 4);  a1 += __shfl_xor(a1, 4);
        a0 += __shfl_xor(a0, 8);  a1 += __shfl_xor(a1, 8);
        a0 += __shfl_xor(a0, 16); a1 += __shfl_xor(a1, 16);
        a0 += __shfl_xor(a0, 32); a1 += __shfl_xor(a1, 32);
        if (lane == 0) { ssc[s0] = a0 + vab; ssc[s0 + 1] = a1 + vab; }
    }
    __syncthreads();
    if (tid < 128) {
        float mx = -1e30f;
        #pragma unroll 8
        for (int s = 0; s < 128; ++s) mx = fmaxf(mx, ssc[s]);
        float sum = 0.f;
        #pragma unroll 8
        for (int s = 0; s < 128; ++s) sum += __expf(ssc[s] - mx);
        float wvv = __expf(ssc[tid] - mx) / sum;
        sw[tid] = wvv;
        if (q == 0) attns[((size_t)b * T + t) * S + tid] = wvv;
    }
    __syncthreads();

    const int j0 = q * 256 + lane * 4;
    float ar[4] = {}, az[4] = {}, an[4] = {};
    const unsigned short* kvb = KV + (size_t)b * S * H3 + j0;
    for (int i = 0; i < 32; i += 2) {
        int s0 = wv * 32 + i;
        float w0 = sw[s0], w1 = sw[s0 + 1];
        const unsigned short* r0 = kvb + (size_t)s0 * H3;
        const unsigned short* r1 = r0 + H3;
        uint2 u0a = *reinterpret_cast<const uint2*>(r0);
        uint2 u1a = *reinterpret_cast<const uint2*>(r0 + 1024);
        uint2 u2a = *reinterpret_cast<const uint2*>(r0 + 2048);
        uint2 u0b = *reinterpret_cast<const uint2*>(r1);
        uint2 u1b = *reinterpret_cast<const uint2*>(r1 + 1024);
        uint2 u2b = *reinterpret_cast<const uint2*>(r1 + 2048);
        ar[0] += w0 * b2f((unsigned short)(u0a.x & 0xffff)) + w1 * b2f((unsigned short)(u0b.x & 0xffff));
        ar[1] += w0 * b2f((unsigned short)(u0a.x >> 16))    + w1 * b2f((unsigned short)(u0b.x >> 16));
        ar[2] += w0 * b2f((unsigned short)(u0a.y & 0xffff)) + w1 * b2f((unsigned short)(u0b.y & 0xffff));
        ar[3] += w0 * b2f((unsigned short)(u0a.y >> 16))    + w1 * b2f((unsigned short)(u0b.y >> 16));
        az[0] += w0 * b2f((unsigned short)(u1a.x & 0xffff)) + w1 * b2f((unsigned short)(u1b.x & 0xffff));
        az[1] += w0 * b2f((unsigned short)(u1a.x >> 16))    + w1 * b2f((unsigned short)(u1b.x >> 16));
        az[2] += w0 * b2f((unsigned short)(u1a.y & 0xffff)) + w1 * b2f((unsigned short)(u1b.y & 0xffff));
        az[3] += w0 * b2f((unsigned short)(u1a.y >> 16))    + w1 * b2f((unsigned short)(u1b.y >> 16));
        an[0] += w0 * b2f((unsigned short)(u2a.x & 0xffff)) + w1 * b2f((unsigned short)(u2b.x & 0xffff));
        an[1] += w0 * b2f((unsigned short)(u2a.x >> 16))    + w1 * b2f((unsigned short)(u2b.x >> 16));
        an[2] += w0 * b2f((unsigned short)(u2a.y & 0xffff)) + w1 * b2f((unsigned short)(u2b.y & 0xffff));
        an[3] += w0 * b2f((unsigned short)(u2a.y >> 16))    + w1 * b2f((unsigned short)(u2b.y >> 16));
    }
    #pragma unroll
    for (int g = 0; g < 4; ++g) {
        red[wv][lane][g]     = ar[g];
        red[wv][lane][4 + g] = az[g];
        red[wv][lane][8 + g] = an[g];
    }
    __syncthreads();

    if (tid < 64) {
        float rr[4], zz[4], nn[4];
        #pragma unroll
        for (int g = 0; g < 4; ++g) {
            rr[g] = red[0][tid][g] + red[1][tid][g] + red[2][tid][g] + red[3][tid][g];
            zz[g] = red[0][tid][4+g] + red[1][tid][4+g] + red[2][tid][4+g] + red[3][tid][4+g];
            nn[g] = red[0][tid][8+g] + red[1][tid][8+g] + red[2][tid][8+g] + red[3][tid][8+g];
        }
        const int jj = q * 256 + tid * 4;
        const float* ge = gi_emb + ((size_t)t * B + b) * H3;
        const float* gh = ghq + (size_t)b * 4096;
        float geR[4], geZ[4], geN[4], ghR[4], ghZ[4], ghN[4], hv[4];
        *reinterpret_cast<float4*>(geR) = *reinterpret_cast<const float4*>(ge + jj);
        *reinterpret_cast<float4*>(geZ) = *reinterpret_cast<const float4*>(ge + 1024 + jj);
        *reinterpret_cast<float4*>(geN) = *reinterpret_cast<const float4*>(ge + 2048 + jj);
        *reinterpret_cast<float4*>(ghR) = *reinterpret_cast<const float4*>(gh + jj);
        *reinterpret_cast<float4*>(ghZ) = *reinterpret_cast<const float4*>(gh + 1024 + jj);
        *reinterpret_cast<float4*>(ghN) = *reinterpret_cast<const float4*>(gh + 2048 + jj);
        *reinterpret_cast<float4*>(hv)  = *reinterpret_cast<const float4*>(h + (size_t)b * H + jj);
        ushort4 hb;
        unsigned short* hbp = reinterpret_cast<unsigned short*>(&hb);
        #pragma unroll
        for (int i = 0; i < 4; ++i) {
            float r = fast_sigmoid(geR[i] + rr[i] + ghR[i]);
            float z = fast_sigmoid(geZ[i] + zz[i] + ghZ[i]);
            float n = fast_tanh(geN[i] + nn[i] + r * ghN[i]);
            hv[i] = (1.f - z) * n + z * hv[i];
            hbp[i] = f2b(hv[i]);
        }
        *reinterpret_cast<float4*>(h + (size_t)b * H + jj) = *reinterpret_cast<float4*>(hv);
        *reinterpret_cast<ushort4*>(hbf + (size_t)b * H + jj) = hb;
        *reinterpret_cast<ushort4*>(outs_bf + ((size_t)b * T + t) * H + jj) = hb;
        if (t == T - 1)
            *reinterpret_cast<float4*>(h_final + (size_t)b * H + jj) = *reinterpret_cast<float4*>(hv);
    }
}

// ---------------- fused LSE + subtract ----------------
__global__ void lsesub_kernel(const float2* __restrict__ stats, float* __restrict__ x) {
    const int row = blockIdx.x;
    const int tid = threadIdx.x;
    __shared__ float shm[256];
    __shared__ float shs[256];
    float mv = -1e30f, sv = 0.f;
    float2 st = make_float2(-1e30f, 0.f);
    if (tid < NCHUNK) { st = stats[(size_t)row * NCHUNK + tid]; mv = st.x; }
    shm[tid] = mv; __syncthreads();
    for (int off = 128; off > 0; off >>= 1) {
        if (tid < off) shm[tid] = fmaxf(shm[tid], shm[tid + off]);
        __syncthreads();
    }
    float M = shm[0]; __syncthreads();
    if (tid < NCHUNK) sv = st.y * expf(st.x - M);
    shs[tid] = sv; __syncthreads();
    for (int off = 128; off > 0; off >>= 1) {
        if (tid < off) shs[tid] += shs[tid + off];
        __syncthreads();
    }
    float L = M + logf(shs[0]);
    __syncthreads();
    float4* p = reinterpret_cast<float4*>(x + (size_t)row * V);
    for (int i = tid; i < V / 4; i += 256) {
        float4 v = p[i];
        v.x -= L; v.y -= L; v.z -= L; v.w -= L;
        p[i] = v;
    }
}

// ---------------- host ----------------

extern "C" void kernel_launch(void* const* d_in, const int* in_sizes, int n_in,
                              void* d_out, int out_size, void* d_ws, size_t ws_size,
                              hipStream_t stream) {
    const float* enc   = (const float*)d_in[0];
    const float* h0    = (const float*)d_in[1];
    const int*   tgt   = (const int*)d_in[2];
    const float* emb   = (const float*)d_in[3];
    const float* Wa_w  = (const float*)d_in[4];
    const float* Wa_b  = (const float*)d_in[5];
    const float* Ua_w  = (const float*)d_in[6];
    const float* Ua_b  = (const float*)d_in[7];
    const float* Va_w  = (const float*)d_in[8];
    const float* Va_b  = (const float*)d_in[9];
    const float* gwi   = (const float*)d_in[10];
    const float* gwh   = (const float*)d_in[11];
    const float* gbi   = (const float*)d_in[12];
    const float* gbh   = (const float*)d_in[13];
    const float* out_w = (const float*)d_in[14];
    const float* out_b = (const float*)d_in[15];

    float* out       = (float*)d_out;
    float* log_probs = out;                          // [B*T, V]
    float* h_final   = out + (size_t)B * T * V;      // [B, H]
    float* attns     = h_final + (size_t)B * H;      // [B, T, S]

    char* pp = (char*)d_ws;
    auto alloc = [&](size_t bytes) { char* r = pp; pp += (bytes + 255) & ~(size_t)255; return r; };
    unsigned short* ua_bf   = (unsigned short*)alloc((size_t)B * S * H * 2);
    unsigned short* enc_bf  = (unsigned short*)alloc((size_t)B * S * H * 2);
    unsigned short* outw_bf = (unsigned short*)alloc((size_t)V * H * 2);
    unsigned short* KV      = (unsigned short*)alloc((size_t)B * S * H3 * 2);
    unsigned short* Ua_bf   = (unsigned short*)alloc((size_t)H * H * 2);
    unsigned short* Wcat    = (unsigned short*)alloc((size_t)4096 * H * 2);
    unsigned short* Wctx    = (unsigned short*)alloc((size_t)H3 * H * 2);
    unsigned short* Wemb    = (unsigned short*)alloc((size_t)H3 * H * 2);
    float*          catbias = (float*)alloc(4096 * 4);
    unsigned short* embg    = (unsigned short*)alloc((size_t)T * B * H * 2);
    float*          gi_emb  = (float*)alloc((size_t)T * B * H3 * 4);
    float*          hbuf    = (float*)alloc((size_t)B * H * 4);
    unsigned short* hbf     = (unsigned short*)alloc((size_t)B * H * 2);
    float*          ghq     = (float*)alloc((size_t)B * 4096 * 4);
    unsigned short* outs_bf = (unsigned short*)alloc((size_t)B * T * H * 2);
    float2*         stats   = (float2*)alloc((size_t)B * T * NCHUNK * 8);

    prep_kernel<<<PREP_NB, 256, 0, stream>>>(enc, enc_bf, Ua_w, Ua_bf,
                                             gwh, Wa_w, Wcat, gwi, Wemb, Wctx,
                                             gbh, Wa_b, catbias, emb, tgt, embg,
                                             h0, hbf, hbuf);

    GemmDesc d0 = { enc_bf, Ua_bf, Ua_b, (void*)ua_bf,  B * S, H,  1 };
    GemmDesc d1 = { enc_bf, Wctx,  nullptr, (void*)KV,  B * S, H3, 1 };
    GemmDesc d2 = { embg,   Wemb,  gbi, (void*)gi_emb,  T * B, H3, 0 };
    gemm3_kernel<<<2168, 512, 0, stream>>>(d0, d1, d2);

    for (int t = 0; t < T; ++t) {
        gemm_smallA<<<128, 256, 0, stream>>>(hbf, Wcat, catbias, ghq);
        stepB<<<256 + CONV_BLKS, 256, 0, stream>>>(ghq, ua_bf, KV, Va_w, Va_b, gi_emb,
                                                   hbuf, hbf, outs_bf, attns, h_final,
                                                   out_w, outw_bf, t);
    }

    gemm_logits<<<(B * T / 128) * (V / 128), 512, 0, stream>>>(
        outs_bf, outw_bf, out_b, log_probs, stats, B * T, V, H);
    lsesub_kernel<<<B * T, 256, 0, stream>>>(stats, log_probs);
}